// Round 20
// baseline (1437.637 us; speedup 1.0000x reference)
//
#include <hip/hip_runtime.h>

typedef unsigned int u32;
typedef unsigned short u16;
typedef short bf16x8 __attribute__((ext_vector_type(8)));
typedef float f32x4 __attribute__((ext_vector_type(4)));

#define N_NODES 150000
#define E_EDGES 300000
#define L_CNT   151552   // 74*2048 padded per-layer node stride
#define ETILES  9375     // E/32
#define NTILES  4688     // ceil(N/32)
#define KVBLKS  37500    // E*16/128 chunks at 128 threads
#define PREPB   42192    // 9*4688: interleaved gemm(1/9) + kvin(8/9)
#define SCATB   2344     // E/128 scatter blocks appended

__device__ __forceinline__ float blo(u32 u){ return __uint_as_float(u << 16); }
__device__ __forceinline__ float bhi(u32 u){ return __uint_as_float(u & 0xffff0000u); }
__device__ __forceinline__ float b2f(u16 h){ return __uint_as_float(((u32)h) << 16); }
__device__ __forceinline__ u16 f2bf(float f){
  u32 u = __float_as_uint(f);
  return (u16)((u + 0x7fffu + ((u >> 16) & 1u)) >> 16);   // RNE
}
__device__ __forceinline__ u32 pack2(float a, float b){
  return (u32)f2bf(a) | ((u32)f2bf(b) << 16);
}

__device__ __forceinline__ f32x4 mfma16(bf16x8 a, bf16x8 b, f32x4 c){
  return __builtin_amdgcn_mfma_f32_16x16x32_bf16(a, b, c, 0, 0, 0);
}

// operand tile [r=0..31][k=0..127] u16, XOR-swizzled
__device__ __forceinline__ int opsw(int r, int k){ return (r * 128 + k) ^ ((r & 7) << 3); }
// C tile [r][n] swizzle
__device__ __forceinline__ int csw(int r, int n){ return (r * 128 + n) ^ (((r >> 2) & 3) << 3); }

// ---------------- weight pre-transpose: Wt[n][k] bf16 <- W[k][n] f32 ----------------
__global__ __launch_bounds__(256)
void k_wt(const float* __restrict__ Wq, const float* __restrict__ Wk,
          const float* __restrict__ Wv, const float* __restrict__ Ws,
          u16* __restrict__ Wt)
{
  const int m = blockIdx.x;   // 0..15: [Wq0-3, Wk0-3, Wv0-3, Wsk0-3]
  const float* src = (m < 4 ? Wq : m < 8 ? Wk : m < 12 ? Wv : Ws)
                     + (size_t)(m & 3) * 16384;
  u16* dst = Wt + (size_t)m * 16384;
  const int t = threadIdx.x;
  for (int i = 0; i < 16; ++i) {
    int idx = i * 256 + t;
    int n = idx >> 5;
    int k4 = (idx & 31) << 2;
    ushort4 o;
    o.x = f2bf(src[(k4 + 0) * 128 + n]);
    o.y = f2bf(src[(k4 + 1) * 128 + n]);
    o.z = f2bf(src[(k4 + 2) * 128 + n]);
    o.w = f2bf(src[(k4 + 3) * 128 + n]);
    *(ushort4*)(dst + n * 128 + k4) = o;
  }
}

// ---------------- CSR build (counting sort of edges by dst) ----------------

__global__ __launch_bounds__(256)
void k_hist(const int* __restrict__ eidx, int* __restrict__ counts)
{
  const int l = blockIdx.y;
  const int e = blockIdx.x * 256 + threadIdx.x;
  if (e < E_EDGES) {
    int dst = eidx[(size_t)l * 2 * E_EDGES + E_EDGES + e];
    atomicAdd(&counts[(size_t)l * L_CNT + dst], 1);
  }
}

__global__ __launch_bounds__(256)
void k_scan1(const int* __restrict__ counts, int* __restrict__ rowptr,
             int* __restrict__ bsum)
{
  __shared__ int sh[256];
  const int b = blockIdx.x, l = blockIdx.y;
  const int t = threadIdx.x;
  const int* c = counts + (size_t)l * L_CNT + b * 2048;
  int* rp = rowptr + (size_t)l * L_CNT + b * 2048;
  int v[8]; int s = 0;
  #pragma unroll
  for (int j = 0; j < 8; ++j) { v[j] = c[t * 8 + j]; s += v[j]; }
  sh[t] = s; __syncthreads();
  for (int off = 1; off < 256; off <<= 1) {
    int x = (t >= off) ? sh[t - off] : 0;
    __syncthreads();
    sh[t] += x;
    __syncthreads();
  }
  int excl = (t == 0) ? 0 : sh[t - 1];
  if (t == 255) bsum[l * 128 + b] = sh[255];
  int run = excl;
  #pragma unroll
  for (int j = 0; j < 8; ++j) { rp[t * 8 + j] = run; run += v[j]; }
}

__global__ __launch_bounds__(128)
void k_scan2(int* __restrict__ bsum)
{
  __shared__ int sh[128];
  const int l = blockIdx.x, t = threadIdx.x;
  int v = (t < 74) ? bsum[l * 128 + t] : 0;
  sh[t] = v; __syncthreads();
  for (int off = 1; off < 128; off <<= 1) {
    int x = (t >= off) ? sh[t - off] : 0;
    __syncthreads();
    sh[t] += x;
    __syncthreads();
  }
  int excl = (t == 0) ? 0 : sh[t - 1];
  if (t < 74) bsum[l * 128 + t] = excl;
}

__global__ __launch_bounds__(256)
void k_scan3(int* __restrict__ rowptr, int* __restrict__ tmp,
             const int* __restrict__ bsum)
{
  const int l = blockIdx.y;
  const int q = blockIdx.x * 256 + threadIdx.x;
  int v = rowptr[(size_t)l * L_CNT + q] + bsum[l * 128 + (q >> 11)];
  rowptr[(size_t)l * L_CNT + q] = v;
  tmp[(size_t)l * L_CNT + q] = v;
}

// scatter device body: edge e of layer-list (srcP..attrP) -> dst-sorted meta record
__device__ __forceinline__ void scatter_one(
    int e, const int* __restrict__ srcP, const int* __restrict__ dstP,
    const int* __restrict__ etP, const float* __restrict__ dtP,
    const float* __restrict__ dsP, const float* __restrict__ attrP,
    int* __restrict__ tmpL, u32* __restrict__ meta)
{
  int dst = dstP[e];
  int pos = atomicAdd(&tmpL[dst], 1);
  int src = srcP[e];
  int et  = etP[e];
  float dtn = dtP[e] * (1.0f / 24.0f);
  float dsv = dsP[e];
  float4 aA = *(const float4*)(attrP + (size_t)e * 8);
  float4 aB = *(const float4*)(attrP + (size_t)e * 8 + 4);
  uint4 r0, r1;
  r0.x = (u32)src;
  r0.y = (u32)dst | ((u32)et << 20);
  r0.z = __float_as_uint(dtn);
  r0.w = __float_as_uint(dsv);
  r1.x = pack2(aA.x, aA.y); r1.y = pack2(aA.z, aA.w);
  r1.z = pack2(aB.x, aB.y); r1.w = pack2(aB.z, aB.w);
  u32* mp = meta + (size_t)pos * 8;
  *(uint4*)mp = r0;
  *(uint4*)(mp + 4) = r1;
}

__global__ __launch_bounds__(256)
void k_scatter(const int* __restrict__ srcP, const int* __restrict__ dstP,
               const int* __restrict__ etP, const float* __restrict__ dtP,
               const float* __restrict__ dsP, const float* __restrict__ attrP,
               int* __restrict__ tmpL, u32* __restrict__ meta)
{
  const int e = blockIdx.x * 256 + threadIdx.x;
  if (e < E_EDGES)
    scatter_one(e, srcP, dstP, etP, dtP, dsP, attrP, tmpL, meta);
}

// ---------------- BN stats fold: scsh = {scale[128], shift[128]} ----------------
__global__ __launch_bounds__(128)
void bn_stats(const float* __restrict__ colsum, const float* __restrict__ colsumsq,
              const float* __restrict__ gamma, const float* __restrict__ bvec,
              float* __restrict__ scsh)
{
  const int d = threadIdx.x;
  const float invN = 1.f / 150000.f;
  float mu = colsum[d] * invN;
  float var = colsumsq[d] * invN - mu * mu;
  float sc = gamma[d] * rsqrtf(var + 1e-5f);
  scsh[d] = sc;
  scsh[128 + d] = bvec[d] - mu * sc;
}

// ---------------- combined prep: interleaved gemm + kvin + next-layer scatter --------
// b < PREPB:  b%9==0 -> node GEMM tile b/9; else kvin chunk b-1-b/9 (guarded).
// b >= PREPB: next-layer scatter blocks (only when metaN != nullptr).

template<int XF32, int BN>
__global__ __launch_bounds__(128, 2)
void prep(const void* __restrict__ xg, const u16* __restrict__ WtQ,
          const u16* __restrict__ WtS, const float* __restrict__ scsh,
          u16* __restrict__ Qo, u16* __restrict__ So,
          const float* __restrict__ Wa, const float* __restrict__ tw,
          const float* __restrict__ tb, const float* __restrict__ dw,
          const float* __restrict__ db, const float* __restrict__ ttab,
          const u32* __restrict__ meta, u16* __restrict__ kvV,
          const int* __restrict__ srcN, const int* __restrict__ dstN,
          const int* __restrict__ etN, const float* __restrict__ dtN,
          const float* __restrict__ dsN, const float* __restrict__ attrN,
          int* __restrict__ tmpN, u32* __restrict__ metaN)
{
  __shared__ __align__(16) u16 As[4160];
  __shared__ __align__(16) u16 Bs[4160];
  const int b = blockIdx.x;
  const int t = threadIdx.x;

  if (b >= PREPB) {
    // ---------------- next-layer scatter path ----------------
    int e = (b - PREPB) * 128 + t;
    if (metaN != nullptr && e < E_EDGES)
      scatter_one(e, srcN, dstN, etN, dtN, dsN, attrN, tmpN, metaN);
    return;
  }

  if (b % 9 == 0) {
    // ---------------- node GEMM path (tile = b/9) ----------------
    const int w = t >> 6, lane = t & 63;
    const int lr = lane & 15, hi = lane >> 4;
    const int row0 = (b / 9) * 32;
    const int nr = min(32, N_NODES - row0);
    const u16* Wt = w ? WtS : WtQ;
    u16* C = w ? So : Qo;

    bf16x8 wt[8][4];
    #pragma unroll
    for (int nb = 0; nb < 8; ++nb)
      #pragma unroll
      for (int ks = 0; ks < 4; ++ks)
        wt[nb][ks] = *(const bf16x8*)(Wt + (nb * 16 + lr) * 128 + ks * 32 + hi * 8);

    #pragma unroll
    for (int i = 0; i < 4; ++i) {
      int idx = i * 128 + t;
      int r = idx >> 4, c8 = (idx & 15) << 3;
      if (r < nr) {
        if (XF32) {
          float4 vA = *(const float4*)((const float*)xg + (size_t)(row0 + r) * 128 + c8);
          float4 vB = *(const float4*)((const float*)xg + (size_t)(row0 + r) * 128 + c8 + 4);
          uint4 o;
          o.x = pack2(vA.x, vA.y); o.y = pack2(vA.z, vA.w);
          o.z = pack2(vB.x, vB.y); o.w = pack2(vB.z, vB.w);
          *(uint4*)(As + opsw(r, c8)) = o;
        } else {
          uint4 v = *(const uint4*)((const u16*)xg + (size_t)(row0 + r) * 128 + c8);
          if (BN) {
            float4 scA = *(const float4*)(scsh + c8);
            float4 scB = *(const float4*)(scsh + c8 + 4);
            float4 shA = *(const float4*)(scsh + 128 + c8);
            float4 shB = *(const float4*)(scsh + 128 + c8 + 4);
            float e0v = fmaxf(fmaf(blo(v.x), scA.x, shA.x), 0.f);
            float e1v = fmaxf(fmaf(bhi(v.x), scA.y, shA.y), 0.f);
            float e2v = fmaxf(fmaf(blo(v.y), scA.z, shA.z), 0.f);
            float e3v = fmaxf(fmaf(bhi(v.y), scA.w, shA.w), 0.f);
            float e4v = fmaxf(fmaf(blo(v.z), scB.x, shB.x), 0.f);
            float e5v = fmaxf(fmaf(bhi(v.z), scB.y, shB.y), 0.f);
            float e6v = fmaxf(fmaf(blo(v.w), scB.z, shB.z), 0.f);
            float e7v = fmaxf(fmaf(bhi(v.w), scB.w, shB.w), 0.f);
            v.x = pack2(e0v, e1v); v.y = pack2(e2v, e3v);
            v.z = pack2(e4v, e5v); v.w = pack2(e6v, e7v);
          }
          *(uint4*)(As + opsw(r, c8)) = v;
        }
      } else {
        *(uint4*)(As + opsw(r, c8)) = make_uint4(0, 0, 0, 0);
      }
    }
    __syncthreads();

    f32x4 acc[2][8];
    #pragma unroll
    for (int a = 0; a < 2; ++a)
      #pragma unroll
      for (int bb = 0; bb < 8; ++bb) {
        acc[a][bb][0] = 0.f; acc[a][bb][1] = 0.f;
        acc[a][bb][2] = 0.f; acc[a][bb][3] = 0.f;
      }
    #pragma unroll
    for (int ks = 0; ks < 4; ++ks) {
      const int kb = ks * 32 + hi * 8;
      bf16x8 a0 = *(const bf16x8*)(As + opsw(lr, kb));
      bf16x8 a1 = *(const bf16x8*)(As + opsw(16 + lr, kb));
      #pragma unroll
      for (int nb = 0; nb < 8; ++nb) {
        acc[0][nb] = mfma16(a0, wt[nb][ks], acc[0][nb]);
        acc[1][nb] = mfma16(a1, wt[nb][ks], acc[1][nb]);
      }
    }
    __syncthreads();   // all As reads complete before wave0 overwrites it

    u16* Cs = w ? Bs : As;
    const int g4 = hi << 2;
    #pragma unroll
    for (int mt = 0; mt < 2; ++mt)
      #pragma unroll
      for (int nt = 0; nt < 8; ++nt)
        #pragma unroll
        for (int j = 0; j < 4; ++j)
          Cs[csw(mt * 16 + g4 + j, nt * 16 + lr)] = f2bf(acc[mt][nt][j]);
    #pragma unroll
    for (int i = 0; i < 8; ++i) {
      int idx = i * 64 + lane;
      int r = idx >> 4, n8 = (idx & 15) << 3;
      if (r < nr) {
        uint4 v = *(const uint4*)(Cs + csw(r, n8));
        *(uint4*)(C + (size_t)(row0 + r) * 128 + n8) = v;
      }
    }
  } else {
    // ---------------- kv_in path (one 8-dim chunk per thread) ----------------
    const int blk = b - 1 - (b / 9);
    if (blk >= KVBLKS) return;
    const int idx = blk * 128 + t;   // E*16 chunks
    const int e = idx >> 4;
    const int c8 = (idx & 15) << 3;
    const u32* mp = meta + (size_t)e * 8;
    uint4 m0 = *(const uint4*)mp;
    uint4 m1 = *(const uint4*)(mp + 4);
    const int src = (int)m0.x;
    const int et = (int)(m0.y >> 20);
    const float dtn = __uint_as_float(m0.z);
    const float dss = __uint_as_float(m0.w);
    float aa[8] = { blo(m1.x), bhi(m1.x), blo(m1.y), bhi(m1.y),
                    blo(m1.z), bhi(m1.z), blo(m1.w), bhi(m1.w) };
    const float4 twA = *(const float4*)(tw + c8);
    const float4 twB = *(const float4*)(tw + c8 + 4);
    const float4 tbA = *(const float4*)(tb + c8);
    const float4 tbB = *(const float4*)(tb + c8 + 4);
    const float4 dwA = *(const float4*)(dw + c8);
    const float4 dwB = *(const float4*)(dw + c8 + 4);
    const float4 dbA = *(const float4*)(db + c8);
    const float4 dbB = *(const float4*)(db + c8 + 4);
    const float4 ttA = *(const float4*)(ttab + et * 128 + c8);
    const float4 ttB = *(const float4*)(ttab + et * 128 + c8 + 4);
    float f[8];
    f[0] = __cosf(fmaf(dtn, twA.x, tbA.x)) + __cosf(fmaf(dss, dwA.x, dbA.x)) + ttA.x;
    f[1] = __cosf(fmaf(dtn, twA.y, tbA.y)) + __cosf(fmaf(dss, dwA.y, dbA.y)) + ttA.y;
    f[2] = __cosf(fmaf(dtn, twA.z, tbA.z)) + __cosf(fmaf(dss, dwA.z, dbA.z)) + ttA.z;
    f[3] = __cosf(fmaf(dtn, twA.w, tbA.w)) + __cosf(fmaf(dss, dwA.w, dbA.w)) + ttA.w;
    f[4] = __cosf(fmaf(dtn, twB.x, tbB.x)) + __cosf(fmaf(dss, dwB.x, dbB.x)) + ttB.x;
    f[5] = __cosf(fmaf(dtn, twB.y, tbB.y)) + __cosf(fmaf(dss, dwB.y, dbB.y)) + ttB.y;
    f[6] = __cosf(fmaf(dtn, twB.z, tbB.z)) + __cosf(fmaf(dss, dwB.z, dbB.z)) + ttB.z;
    f[7] = __cosf(fmaf(dtn, twB.w, tbB.w)) + __cosf(fmaf(dss, dwB.w, dbB.w)) + ttB.w;
    #pragma unroll
    for (int a = 0; a < 8; ++a) {
      float4 wA = *(const float4*)(Wa + a * 128 + c8);
      float4 wB = *(const float4*)(Wa + a * 128 + c8 + 4);
      f[0] = fmaf(aa[a], wA.x, f[0]);
      f[1] = fmaf(aa[a], wA.y, f[1]);
      f[2] = fmaf(aa[a], wA.z, f[2]);
      f[3] = fmaf(aa[a], wA.w, f[3]);
      f[4] = fmaf(aa[a], wB.x, f[4]);
      f[5] = fmaf(aa[a], wB.y, f[5]);
      f[6] = fmaf(aa[a], wB.z, f[6]);
      f[7] = fmaf(aa[a], wB.w, f[7]);
    }
    float xv[8];
    if (XF32) {
      float4 xA = *(const float4*)((const float*)xg + (size_t)src * 128 + c8);
      float4 xB = *(const float4*)((const float*)xg + (size_t)src * 128 + c8 + 4);
      xv[0] = xA.x; xv[1] = xA.y; xv[2] = xA.z; xv[3] = xA.w;
      xv[4] = xB.x; xv[5] = xB.y; xv[6] = xB.z; xv[7] = xB.w;
    } else {
      uint4 xr = *(const uint4*)((const u16*)xg + (size_t)src * 128 + c8);
      xv[0] = blo(xr.x); xv[1] = bhi(xr.x); xv[2] = blo(xr.y); xv[3] = bhi(xr.y);
      xv[4] = blo(xr.z); xv[5] = bhi(xr.z); xv[6] = blo(xr.w); xv[7] = bhi(xr.w);
    }
    if (BN) {
      float4 scA = *(const float4*)(scsh + c8);
      float4 scB = *(const float4*)(scsh + c8 + 4);
      float4 shA = *(const float4*)(scsh + 128 + c8);
      float4 shB = *(const float4*)(scsh + 128 + c8 + 4);
      xv[0] = fmaxf(fmaf(xv[0], scA.x, shA.x), 0.f);
      xv[1] = fmaxf(fmaf(xv[1], scA.y, shA.y), 0.f);
      xv[2] = fmaxf(fmaf(xv[2], scA.z, shA.z), 0.f);
      xv[3] = fmaxf(fmaf(xv[3], scA.w, shA.w), 0.f);
      xv[4] = fmaxf(fmaf(xv[4], scB.x, shB.x), 0.f);
      xv[5] = fmaxf(fmaf(xv[5], scB.y, shB.y), 0.f);
      xv[6] = fmaxf(fmaf(xv[6], scB.z, shB.z), 0.f);
      xv[7] = fmaxf(fmaf(xv[7], scB.w, shB.w), 0.f);
    }
    uint4 o;
    o.x = pack2(xv[0] + f[0], xv[1] + f[1]);
    o.y = pack2(xv[2] + f[2], xv[3] + f[3]);
    o.z = pack2(xv[4] + f[4], xv[5] + f[5]);
    o.w = pack2(xv[6] + f[6], xv[7] + f[7]);
    *(uint4*)(kvV + (size_t)e * 128 + c8) = o;
  }
}

// ---------------- edge fused: wave0 = kv-stage + K + logits, wave1 = Q-stage + V ------
// Single tile per block (proven: VGPR 104, no spill, 119 us).

__global__ __launch_bounds__(128, 2)
void edge_kv(const u16* __restrict__ WtK, const u16* __restrict__ WtV,
             const u32* __restrict__ meta, const u16* __restrict__ Qb,
             u16* __restrict__ kvV, float* __restrict__ logits)
{
  __shared__ __align__(16) u16 KVs[4160];  // kv tile
  __shared__ __align__(16) u16 Qs[4160];   // Q[dst] tile; wave1's V C-tile later
  __shared__ int dstSh[32];
  const int t = threadIdx.x;
  const int w = t >> 6, lane = t & 63;
  const int lr = lane & 15, hi = lane >> 4;
  const int e0 = blockIdx.x * 32;
  const u16* Wt = w ? WtV : WtK;

  bf16x8 wt[8][4];
  #pragma unroll
  for (int nb = 0; nb < 8; ++nb)
    #pragma unroll
    for (int ks = 0; ks < 4; ++ks)
      wt[nb][ks] = *(const bf16x8*)(Wt + (nb * 16 + lr) * 128 + ks * 32 + hi * 8);

  if (w == 0) {
    #pragma unroll
    for (int i = 0; i < 8; ++i) {
      int idx = i * 64 + lane;
      int r = idx >> 4, c8 = (idx & 15) << 3;
      uint4 v = *(const uint4*)(kvV + (size_t)(e0 + r) * 128 + c8);
      *(uint4*)(KVs + opsw(r, c8)) = v;
    }
  } else {
    if (lane < 32)
      dstSh[lane] = (int)(meta[(size_t)(e0 + lane) * 8 + 1] & 0xFFFFFu);
    #pragma unroll
    for (int i = 0; i < 8; ++i) {
      int idx = i * 64 + lane;
      int r = idx >> 4, c8 = (idx & 15) << 3;
      int qrow = dstSh[r];
      uint4 qv = *(const uint4*)(Qb + (size_t)qrow * 128 + c8);
      *(uint4*)(Qs + opsw(r, c8)) = qv;
    }
  }
  __syncthreads();

  if (w == 0) {
    #pragma unroll
    for (int eb = 0; eb < 2; ++eb) {
      f32x4 kacc[8];
      #pragma unroll
      for (int b = 0; b < 8; ++b) {
        kacc[b][0] = 0.f; kacc[b][1] = 0.f; kacc[b][2] = 0.f; kacc[b][3] = 0.f;
      }
      #pragma unroll
      for (int ks = 0; ks < 4; ++ks) {
        bf16x8 ef = *(const bf16x8*)(KVs + opsw(eb * 16 + lr, ks * 32 + hi * 8));
        #pragma unroll
        for (int nb = 0; nb < 8; ++nb)
          kacc[nb] = mfma16(wt[nb][ks], ef, kacc[nb]);
      }
      const int el = eb * 16 + lr;
      float hs[4] = {0.f, 0.f, 0.f, 0.f};
      #pragma unroll
      for (int nb = 0; nb < 8; ++nb) {
        ushort4 q = *(const ushort4*)(Qs + opsw(el, nb * 16 + hi * 4));
        hs[nb >> 1] += b2f(q.x) * kacc[nb][0] + b2f(q.y) * kacc[nb][1]
                     + b2f(q.z) * kacc[nb][2] + b2f(q.w) * kacc[nb][3];
      }
      #pragma unroll
      for (int h = 0; h < 4; ++h) {
        hs[h] += __shfl_xor(hs[h], 16, 64);
        hs[h] += __shfl_xor(hs[h], 32, 64);
        hs[h] *= 0.17677669529663687f;                 // 32^-0.5
        hs[h] = (hs[h] >= 0.f) ? hs[h] : 0.2f * hs[h]; // leaky relu
      }
      if (lane < 16)
        *(float4*)(logits + (size_t)(e0 + el) * 4) = make_float4(hs[0], hs[1], hs[2], hs[3]);
    }
    __syncthreads();   // pairs with wave1's barrier: Qs now free for its C tile
  } else {
    f32x4 vacc[2][8];
    #pragma unroll
    for (int a = 0; a < 2; ++a)
      #pragma unroll
      for (int b = 0; b < 8; ++b) {
        vacc[a][b][0] = 0.f; vacc[a][b][1] = 0.f;
        vacc[a][b][2] = 0.f; vacc[a][b][3] = 0.f;
      }
    #pragma unroll
    for (int ks = 0; ks < 4; ++ks) {
      const int kb = ks * 32 + hi * 8;
      bf16x8 a0 = *(const bf16x8*)(KVs + opsw(lr, kb));
      bf16x8 a1 = *(const bf16x8*)(KVs + opsw(16 + lr, kb));
      #pragma unroll
      for (int nb = 0; nb < 8; ++nb) {
        vacc[0][nb] = mfma16(a0, wt[nb][ks], vacc[0][nb]);
        vacc[1][nb] = mfma16(a1, wt[nb][ks], vacc[1][nb]);
      }
    }
    __syncthreads();   // wave0 done reading Qs -> reuse as C tile
    const int g4 = hi << 2;
    #pragma unroll
    for (int mt = 0; mt < 2; ++mt)
      #pragma unroll
      for (int nt = 0; nt < 8; ++nt)
        #pragma unroll
        for (int j = 0; j < 4; ++j)
          Qs[csw(mt * 16 + g4 + j, nt * 16 + lr)] = f2bf(vacc[mt][nt][j]);
    #pragma unroll
    for (int i = 0; i < 8; ++i) {
      int idx = i * 64 + lane;
      int r = idx >> 4, n8 = (idx & 15) << 3;
      uint4 v = *(const uint4*)(Qs + csw(r, n8));
      *(uint4*)(kvV + (size_t)(e0 + r) * 128 + n8) = v;
    }
  }
}

// ---------------- per-node softmax + aggregate + combine + stats ----------------
template<int PREBF16>
__global__ __launch_bounds__(256)
void node_agg(const u16* __restrict__ Vs, const float* __restrict__ logits,
              const int* __restrict__ rowptr, const u16* __restrict__ S,
              const float* __restrict__ betaP, float* __restrict__ pre,
              u16* __restrict__ preb, float* __restrict__ colsum,
              float* __restrict__ colsumsq)
{
  __shared__ float red[1024];
  const int t = threadIdx.x;
  const int g = t >> 5;
  const int lane = t & 31;
  const int d0 = lane * 4;
  const int h = lane >> 3;
  const float beta = *betaP;
  const float omb = 1.f - beta;
  float s4[4] = {0.f, 0.f, 0.f, 0.f};
  float q4[4] = {0.f, 0.f, 0.f, 0.f};
  for (int rep = 0; rep < 16; ++rep) {
    int n = blockIdx.x * 128 + rep * 8 + g;
    if (n < N_NODES) {
      int rs = rowptr[n], re = rowptr[n + 1];
      float m = -1e30f;
      for (int i = rs; i < re; ++i)
        m = fmaxf(m, logits[(size_t)i * 4 + h]);
      float den = 0.f;
      float a0 = 0.f, a1 = 0.f, a2 = 0.f, a3 = 0.f;
      for (int i = rs; i < re; ++i) {
        float wgt = __expf(logits[(size_t)i * 4 + h] - m);
        den += wgt;
        ushort4 v = *(const ushort4*)(Vs + (size_t)i * 128 + d0);
        a0 = fmaf(wgt, b2f(v.x), a0);
        a1 = fmaf(wgt, b2f(v.y), a1);
        a2 = fmaf(wgt, b2f(v.z), a2);
        a3 = fmaf(wgt, b2f(v.w), a3);
      }
      float inv = (den > 0.f) ? (omb / den) : 0.f;
      ushort4 sv = *(const ushort4*)(S + (size_t)n * 128 + d0);
      float p0 = fmaf(beta, b2f(sv.x), a0 * inv);
      float p1 = fmaf(beta, b2f(sv.y), a1 * inv);
      float p2 = fmaf(beta, b2f(sv.z), a2 * inv);
      float p3 = fmaf(beta, b2f(sv.w), a3 * inv);
      if (PREBF16) {
        ushort4 o;
        o.x = f2bf(p0); o.y = f2bf(p1); o.z = f2bf(p2); o.w = f2bf(p3);
        *(ushort4*)(preb + (size_t)n * 128 + d0) = o;
      } else {
        *(float4*)(pre + (size_t)n * 128 + d0) = make_float4(p0, p1, p2, p3);
      }
      s4[0] += p0; s4[1] += p1; s4[2] += p2; s4[3] += p3;
      q4[0] += p0 * p0; q4[1] += p1 * p1; q4[2] += p2 * p2; q4[3] += p3 * p3;
    }
  }
  *(float4*)(&red[g * 128 + d0]) = make_float4(s4[0], s4[1], s4[2], s4[3]);
  __syncthreads();
  if (t < 128) {
    float tot = 0.f;
    #pragma unroll
    for (int gg = 0; gg < 8; ++gg) tot += red[gg * 128 + t];
    atomicAdd(&colsum[t], tot);
  }
  __syncthreads();
  *(float4*)(&red[g * 128 + d0]) = make_float4(q4[0], q4[1], q4[2], q4[3]);
  __syncthreads();
  if (t < 128) {
    float tot = 0.f;
    #pragma unroll
    for (int gg = 0; gg < 8; ++gg) tot += red[gg * 128 + t];
    atomicAdd(&colsumsq[t], tot);
  }
}

// ---------------- BatchNorm + ReLU for the LAST layer (f32 in d_out) ----------------
__global__ __launch_bounds__(256)
void bn_apply(const float* __restrict__ pre, const float* __restrict__ colsum,
              const float* __restrict__ colsumsq, const float* __restrict__ gamma,
              const float* __restrict__ bvec, float* __restrict__ outf)
{
  const int idx = blockIdx.x * 256 + threadIdx.x;
  const int n = idx >> 5;
  const int d0 = (idx & 31) * 4;
  const float invN = 1.f / 150000.f;
  float4 p = *(const float4*)(pre + (size_t)n * 128 + d0);
  float4 cs = *(const float4*)(colsum + d0);
  float4 cq = *(const float4*)(colsumsq + d0);
  float4 gm = *(const float4*)(gamma + d0);
  float4 bv = *(const float4*)(bvec + d0);
  float mu, var, y;
  mu = cs.x * invN; var = cq.x * invN - mu * mu;
  y = (p.x - mu) * rsqrtf(var + 1e-5f) * gm.x + bv.x; p.x = fmaxf(y, 0.f);
  mu = cs.y * invN; var = cq.y * invN - mu * mu;
  y = (p.y - mu) * rsqrtf(var + 1e-5f) * gm.y + bv.y; p.y = fmaxf(y, 0.f);
  mu = cs.z * invN; var = cq.z * invN - mu * mu;
  y = (p.z - mu) * rsqrtf(var + 1e-5f) * gm.z + bv.z; p.z = fmaxf(y, 0.f);
  mu = cs.w * invN; var = cq.w * invN - mu * mu;
  y = (p.w - mu) * rsqrtf(var + 1e-5f) * gm.w + bv.w; p.w = fmaxf(y, 0.f);
  *(float4*)(outf + (size_t)n * 128 + d0) = p;
}

extern "C" void kernel_launch(void* const* d_in, const int* in_sizes, int n_in,
                              void* d_out, int out_size, void* d_ws, size_t ws_size,
                              hipStream_t stream)
{
  const float* x0    = (const float*)d_in[0];
  const float* Wq    = (const float*)d_in[1];
  const float* Wk    = (const float*)d_in[2];
  const float* Wv    = (const float*)d_in[3];
  const float* Wsk   = (const float*)d_in[4];
  const float* Wa    = (const float*)d_in[5];
  const float* tw    = (const float*)d_in[6];
  const float* tb    = (const float*)d_in[7];
  const float* dw    = (const float*)d_in[8];
  const float* db    = (const float*)d_in[9];
  const float* ttab  = (const float*)d_in[10];
  const float* gam   = (const float*)d_in[11];
  const float* bet   = (const float*)d_in[12];
  const float* betaP = (const float*)d_in[13];
  const float* attr  = (const float*)d_in[14];
  const float* dt    = (const float*)d_in[15];
  const float* dsv   = (const float*)d_in[16];
  const int*   eidx  = (const int*)d_in[17];
  const int*   etyp  = (const int*)d_in[18];

  // workspace ~222 MB
  char* p = (char*)d_ws;
  u16* xbf  = (u16*)p;       p += 38400000;          // [N,128] bf16: pre of previous layer
  u16* Q    = (u16*)p;       p += 38400000;          // [N,128] bf16
  u16* S    = (u16*)p;       p += 38400000;          // [N,128] bf16
  u16* kvV  = (u16*)p;       p += 76800000;          // [E,128] bf16: kv_in, then V (in place)
  float* logits = (float*)p; p += 4800000;           // [E,4] f32 dst-sorted
  int* rowptr = (int*)p;     p += 4 * L_CNT * 4;
  int* tmp    = (int*)p;     p += 4 * L_CNT * 4;
  int* bsum   = (int*)p;     p += 4 * 128 * 4;
  float* colsum   = (float*)p; p += 512;
  float* colsumsq = (float*)p; p += 512;
  float* scsh     = (float*)p; p += 1024;            // {scale[128], shift[128]}
  u16* Wt = (u16*)p;         p += 16 * 16384 * 2;    // 16 transposed bf16 weights
  u32* metaA = (u32*)p;      p += (size_t)E_EDGES * 32;  // 32B/edge, ping
  u32* metaB = (u32*)p;      p += (size_t)E_EDGES * 32;  // pong

  float* pre = (float*)d_out;   // [N,128] f32 scratch for LAST layer

  // weight transpose + CSR build (once) + layer-0 scatter
  k_wt<<<16, 256, 0, stream>>>(Wq, Wk, Wv, Wsk, Wt);
  hipMemsetAsync(tmp, 0, 4 * L_CNT * 4, stream);
  k_hist<<<dim3(1172, 4), 256, 0, stream>>>(eidx, tmp);
  k_scan1<<<dim3(74, 4), 256, 0, stream>>>(tmp, rowptr, bsum);
  k_scan2<<<4, 128, 0, stream>>>(bsum);
  k_scan3<<<dim3(592, 4), 256, 0, stream>>>(rowptr, tmp, bsum);
  k_scatter<<<1172, 256, 0, stream>>>(
      eidx, eidx + 300000, etyp, dt, dsv, attr, tmp, metaA);

  for (int l = 0; l < 4; ++l) {
    const int* rpl = rowptr + (size_t)l * L_CNT;
    const u16* WtQl = Wt + (size_t)l * 16384;
    const u16* WtKl = Wt + (size_t)(4 + l) * 16384;
    const u16* WtVl = Wt + (size_t)(8 + l) * 16384;
    const u16* WtSl = Wt + (size_t)(12 + l) * 16384;
    const float* Wal = Wa + (size_t)l * 1024;
    u32* metaCur = (l & 1) ? metaB : metaA;
    u32* metaNxt = (l & 1) ? metaA : metaB;
    const int ln = l + 1;
    const int* srcN = eidx + (size_t)ln * 600000;
    const int* dstN = srcN + 300000;

    hipMemsetAsync(colsum, 0, 1024, stream);

    const int prepGrid = PREPB + ((l < 3) ? SCATB : 0);
    if (l == 0) {
      prep<1, 0><<<prepGrid, 128, 0, stream>>>(
          (const void*)x0, WtQl, WtSl, scsh, Q, S,
          Wal, tw, tb, dw, db, ttab, metaCur, kvV,
          srcN, dstN, etyp + (size_t)ln * 300000, dt + (size_t)ln * 300000,
          dsv + (size_t)ln * 300000, attr + (size_t)ln * 2400000,
          tmp + (size_t)ln * L_CNT, metaNxt);
    } else if (l < 3) {
      prep<0, 1><<<prepGrid, 128, 0, stream>>>(
          (const void*)xbf, WtQl, WtSl, scsh, Q, S,
          Wal, tw, tb, dw, db, ttab, metaCur, kvV,
          srcN, dstN, etyp + (size_t)ln * 300000, dt + (size_t)ln * 300000,
          dsv + (size_t)ln * 300000, attr + (size_t)ln * 2400000,
          tmp + (size_t)ln * L_CNT, metaNxt);
    } else {
      prep<0, 1><<<prepGrid, 128, 0, stream>>>(
          (const void*)xbf, WtQl, WtSl, scsh, Q, S,
          Wal, tw, tb, dw, db, ttab, metaCur, kvV,
          nullptr, nullptr, nullptr, nullptr, nullptr, nullptr,
          nullptr, nullptr);
    }

    edge_kv<<<ETILES, 128, 0, stream>>>(WtKl, WtVl, metaCur, Q, kvV, logits);

    if (l < 3) {
      node_agg<1><<<1172, 256, 0, stream>>>(kvV, logits, rpl, S, betaP + l,
                                            nullptr, xbf, colsum, colsumsq);
      bn_stats<<<1, 128, 0, stream>>>(colsum, colsumsq, gam + (size_t)l * 128,
                                      bet + (size_t)l * 128, scsh);
    } else {
      node_agg<0><<<1172, 256, 0, stream>>>(kvV, logits, rpl, S, betaP + l,
                                            pre, nullptr, colsum, colsumsq);
      bn_apply<<<18750, 256, 0, stream>>>(pre, colsum, colsumsq,
                                          gam + (size_t)l * 128,
                                          bet + (size_t)l * 128, (float*)d_out);
    }
  }
}

// Round 21
// 1427.103 us; speedup vs baseline: 1.0074x; 1.0074x over previous
//
#include <hip/hip_runtime.h>

typedef unsigned int u32;
typedef unsigned short u16;
typedef short bf16x8 __attribute__((ext_vector_type(8)));
typedef float f32x4 __attribute__((ext_vector_type(4)));

#define N_NODES 150000
#define E_EDGES 300000
#define L_CNT   151552   // 74*2048 padded per-layer node stride
#define ETILES  9375     // E/32
#define NTILES  4688     // ceil(N/32)
#define KVBLKS  37500    // E*16/128 chunks at 128 threads

__device__ __forceinline__ float blo(u32 u){ return __uint_as_float(u << 16); }
__device__ __forceinline__ float bhi(u32 u){ return __uint_as_float(u & 0xffff0000u); }
__device__ __forceinline__ float b2f(u16 h){ return __uint_as_float(((u32)h) << 16); }
__device__ __forceinline__ u16 f2bf(float f){
  u32 u = __float_as_uint(f);
  return (u16)((u + 0x7fffu + ((u >> 16) & 1u)) >> 16);   // RNE
}
__device__ __forceinline__ u32 pack2(float a, float b){
  return (u32)f2bf(a) | ((u32)f2bf(b) << 16);
}

__device__ __forceinline__ f32x4 mfma16(bf16x8 a, bf16x8 b, f32x4 c){
  return __builtin_amdgcn_mfma_f32_16x16x32_bf16(a, b, c, 0, 0, 0);
}

// operand tile [r=0..31][k=0..127] u16, XOR-swizzled
__device__ __forceinline__ int opsw(int r, int k){ return (r * 128 + k) ^ ((r & 7) << 3); }
// C tile [r][n] swizzle
__device__ __forceinline__ int csw(int r, int n){ return (r * 128 + n) ^ (((r >> 2) & 3) << 3); }

// ---------------- weight pre-transpose: Wt[n][k] bf16 <- W[k][n] f32 ----------------
__global__ __launch_bounds__(256)
void k_wt(const float* __restrict__ Wq, const float* __restrict__ Wk,
          const float* __restrict__ Wv, const float* __restrict__ Ws,
          u16* __restrict__ Wt)
{
  const int m = blockIdx.x;   // 0..15: [Wq0-3, Wk0-3, Wv0-3, Wsk0-3]
  const float* src = (m < 4 ? Wq : m < 8 ? Wk : m < 12 ? Wv : Ws)
                     + (size_t)(m & 3) * 16384;
  u16* dst = Wt + (size_t)m * 16384;
  const int t = threadIdx.x;
  for (int i = 0; i < 16; ++i) {
    int idx = i * 256 + t;
    int n = idx >> 5;
    int k4 = (idx & 31) << 2;
    ushort4 o;
    o.x = f2bf(src[(k4 + 0) * 128 + n]);
    o.y = f2bf(src[(k4 + 1) * 128 + n]);
    o.z = f2bf(src[(k4 + 2) * 128 + n]);
    o.w = f2bf(src[(k4 + 3) * 128 + n]);
    *(ushort4*)(dst + n * 128 + k4) = o;
  }
}

// ---------------- CSR build (counting sort of edges by dst) ----------------

__global__ __launch_bounds__(256)
void k_hist(const int* __restrict__ eidx, int* __restrict__ counts)
{
  const int l = blockIdx.y;
  const int e = blockIdx.x * 256 + threadIdx.x;
  if (e < E_EDGES) {
    int dst = eidx[(size_t)l * 2 * E_EDGES + E_EDGES + e];
    atomicAdd(&counts[(size_t)l * L_CNT + dst], 1);
  }
}

__global__ __launch_bounds__(256)
void k_scan1(const int* __restrict__ counts, int* __restrict__ rowptr,
             int* __restrict__ bsum)
{
  __shared__ int sh[256];
  const int b = blockIdx.x, l = blockIdx.y;
  const int t = threadIdx.x;
  const int* c = counts + (size_t)l * L_CNT + b * 2048;
  int* rp = rowptr + (size_t)l * L_CNT + b * 2048;
  int v[8]; int s = 0;
  #pragma unroll
  for (int j = 0; j < 8; ++j) { v[j] = c[t * 8 + j]; s += v[j]; }
  sh[t] = s; __syncthreads();
  for (int off = 1; off < 256; off <<= 1) {
    int x = (t >= off) ? sh[t - off] : 0;
    __syncthreads();
    sh[t] += x;
    __syncthreads();
  }
  int excl = (t == 0) ? 0 : sh[t - 1];
  if (t == 255) bsum[l * 128 + b] = sh[255];
  int run = excl;
  #pragma unroll
  for (int j = 0; j < 8; ++j) { rp[t * 8 + j] = run; run += v[j]; }
}

__global__ __launch_bounds__(128)
void k_scan2(int* __restrict__ bsum)
{
  __shared__ int sh[128];
  const int l = blockIdx.x, t = threadIdx.x;
  int v = (t < 74) ? bsum[l * 128 + t] : 0;
  sh[t] = v; __syncthreads();
  for (int off = 1; off < 128; off <<= 1) {
    int x = (t >= off) ? sh[t - off] : 0;
    __syncthreads();
    sh[t] += x;
    __syncthreads();
  }
  int excl = (t == 0) ? 0 : sh[t - 1];
  if (t < 74) bsum[l * 128 + t] = excl;
}

__global__ __launch_bounds__(256)
void k_scan3(int* __restrict__ rowptr, int* __restrict__ tmp,
             const int* __restrict__ bsum)
{
  const int l = blockIdx.y;
  const int q = blockIdx.x * 256 + threadIdx.x;
  int v = rowptr[(size_t)l * L_CNT + q] + bsum[l * 128 + (q >> 11)];
  rowptr[(size_t)l * L_CNT + q] = v;
  tmp[(size_t)l * L_CNT + q] = v;
}

// scatter edges into dst-sorted order, materializing a 32B meta record:
// r0 = {src, dst | et<<20, dt/24, ds}; r1 = attr as bf16x8.
__global__ __launch_bounds__(256)
void k_scatter(const int* __restrict__ srcP, const int* __restrict__ dstP,
               const int* __restrict__ etP, const float* __restrict__ dtP,
               const float* __restrict__ dsP, const float* __restrict__ attrP,
               int* __restrict__ tmpL, u32* __restrict__ meta)
{
  const int e = blockIdx.x * 256 + threadIdx.x;
  if (e < E_EDGES) {
    int dst = dstP[e];
    int pos = atomicAdd(&tmpL[dst], 1);
    int src = srcP[e];
    int et  = etP[e];
    float dtn = dtP[e] * (1.0f / 24.0f);
    float dsv = dsP[e];
    float4 aA = *(const float4*)(attrP + (size_t)e * 8);
    float4 aB = *(const float4*)(attrP + (size_t)e * 8 + 4);
    uint4 r0, r1;
    r0.x = (u32)src;
    r0.y = (u32)dst | ((u32)et << 20);
    r0.z = __float_as_uint(dtn);
    r0.w = __float_as_uint(dsv);
    r1.x = pack2(aA.x, aA.y); r1.y = pack2(aA.z, aA.w);
    r1.z = pack2(aB.x, aB.y); r1.w = pack2(aB.z, aB.w);
    u32* mp = meta + (size_t)pos * 8;
    *(uint4*)mp = r0;
    *(uint4*)(mp + 4) = r1;
  }
}

// ---------------- BN stats fold: scsh = {scale[128], shift[128]} ----------------
__global__ __launch_bounds__(128)
void bn_stats(const float* __restrict__ colsum, const float* __restrict__ colsumsq,
              const float* __restrict__ gamma, const float* __restrict__ bvec,
              float* __restrict__ scsh)
{
  const int d = threadIdx.x;
  const float invN = 1.f / 150000.f;
  float mu = colsum[d] * invN;
  float var = colsumsq[d] * invN - mu * mu;
  float sc = gamma[d] * rsqrtf(var + 1e-5f);
  scsh[d] = sc;
  scsh[128 + d] = bvec[d] - mu * sc;
}

// ---------------- combined prep: gemm_qs blocks + kv_in blocks in ONE launch ----------
// blockIdx.x < NTILES : node GEMM tile (wave0 -> Q, wave1 -> S), proven body.
// blockIdx.x >= NTILES: kv_in feature chunks (128 threads), proven body.
// Independent work; packing them lets BW-bound kvin blocks fill gemm stalls.

template<int XF32, int BN>
__global__ __launch_bounds__(128, 2)
void prep(const void* __restrict__ xg, const u16* __restrict__ WtQ,
          const u16* __restrict__ WtS, const float* __restrict__ scsh,
          u16* __restrict__ Qo, u16* __restrict__ So,
          const float* __restrict__ Wa, const float* __restrict__ tw,
          const float* __restrict__ tb, const float* __restrict__ dw,
          const float* __restrict__ db, const float* __restrict__ ttab,
          const u32* __restrict__ meta, u16* __restrict__ kvV)
{
  __shared__ __align__(16) u16 As[4160];
  __shared__ __align__(16) u16 Bs[4160];
  const int t = threadIdx.x;

  if (blockIdx.x < NTILES) {
    // ---------------- node GEMM path ----------------
    const int w = t >> 6, lane = t & 63;
    const int lr = lane & 15, hi = lane >> 4;
    const int row0 = blockIdx.x * 32;
    const int nr = min(32, N_NODES - row0);
    const u16* Wt = w ? WtS : WtQ;
    u16* C = w ? So : Qo;

    bf16x8 wt[8][4];
    #pragma unroll
    for (int nb = 0; nb < 8; ++nb)
      #pragma unroll
      for (int ks = 0; ks < 4; ++ks)
        wt[nb][ks] = *(const bf16x8*)(Wt + (nb * 16 + lr) * 128 + ks * 32 + hi * 8);

    #pragma unroll
    for (int i = 0; i < 4; ++i) {
      int idx = i * 128 + t;
      int r = idx >> 4, c8 = (idx & 15) << 3;
      if (r < nr) {
        if (XF32) {
          float4 vA = *(const float4*)((const float*)xg + (size_t)(row0 + r) * 128 + c8);
          float4 vB = *(const float4*)((const float*)xg + (size_t)(row0 + r) * 128 + c8 + 4);
          uint4 o;
          o.x = pack2(vA.x, vA.y); o.y = pack2(vA.z, vA.w);
          o.z = pack2(vB.x, vB.y); o.w = pack2(vB.z, vB.w);
          *(uint4*)(As + opsw(r, c8)) = o;
        } else {
          uint4 v = *(const uint4*)((const u16*)xg + (size_t)(row0 + r) * 128 + c8);
          if (BN) {
            float4 scA = *(const float4*)(scsh + c8);
            float4 scB = *(const float4*)(scsh + c8 + 4);
            float4 shA = *(const float4*)(scsh + 128 + c8);
            float4 shB = *(const float4*)(scsh + 128 + c8 + 4);
            float e0v = fmaxf(fmaf(blo(v.x), scA.x, shA.x), 0.f);
            float e1v = fmaxf(fmaf(bhi(v.x), scA.y, shA.y), 0.f);
            float e2v = fmaxf(fmaf(blo(v.y), scA.z, shA.z), 0.f);
            float e3v = fmaxf(fmaf(bhi(v.y), scA.w, shA.w), 0.f);
            float e4v = fmaxf(fmaf(blo(v.z), scB.x, shB.x), 0.f);
            float e5v = fmaxf(fmaf(bhi(v.z), scB.y, shB.y), 0.f);
            float e6v = fmaxf(fmaf(blo(v.w), scB.z, shB.z), 0.f);
            float e7v = fmaxf(fmaf(bhi(v.w), scB.w, shB.w), 0.f);
            v.x = pack2(e0v, e1v); v.y = pack2(e2v, e3v);
            v.z = pack2(e4v, e5v); v.w = pack2(e6v, e7v);
          }
          *(uint4*)(As + opsw(r, c8)) = v;
        }
      } else {
        *(uint4*)(As + opsw(r, c8)) = make_uint4(0, 0, 0, 0);
      }
    }
    __syncthreads();

    f32x4 acc[2][8];
    #pragma unroll
    for (int a = 0; a < 2; ++a)
      #pragma unroll
      for (int b = 0; b < 8; ++b) {
        acc[a][b][0] = 0.f; acc[a][b][1] = 0.f;
        acc[a][b][2] = 0.f; acc[a][b][3] = 0.f;
      }
    #pragma unroll
    for (int ks = 0; ks < 4; ++ks) {
      const int kb = ks * 32 + hi * 8;
      bf16x8 a0 = *(const bf16x8*)(As + opsw(lr, kb));
      bf16x8 a1 = *(const bf16x8*)(As + opsw(16 + lr, kb));
      #pragma unroll
      for (int nb = 0; nb < 8; ++nb) {
        acc[0][nb] = mfma16(a0, wt[nb][ks], acc[0][nb]);
        acc[1][nb] = mfma16(a1, wt[nb][ks], acc[1][nb]);
      }
    }
    __syncthreads();   // all As reads complete before wave0 overwrites it

    u16* Cs = w ? Bs : As;
    const int g4 = hi << 2;
    #pragma unroll
    for (int mt = 0; mt < 2; ++mt)
      #pragma unroll
      for (int nt = 0; nt < 8; ++nt)
        #pragma unroll
        for (int j = 0; j < 4; ++j)
          Cs[csw(mt * 16 + g4 + j, nt * 16 + lr)] = f2bf(acc[mt][nt][j]);
    #pragma unroll
    for (int i = 0; i < 8; ++i) {
      int idx = i * 64 + lane;
      int r = idx >> 4, n8 = (idx & 15) << 3;
      if (r < nr) {
        uint4 v = *(const uint4*)(Cs + csw(r, n8));
        *(uint4*)(C + (size_t)(row0 + r) * 128 + n8) = v;
      }
    }
  } else {
    // ---------------- kv_in path (one 8-dim chunk per thread) ----------------
    const int idx = (blockIdx.x - NTILES) * 128 + t;   // E*16 chunks
    const int e = idx >> 4;
    const int c8 = (idx & 15) << 3;
    const u32* mp = meta + (size_t)e * 8;
    uint4 m0 = *(const uint4*)mp;
    uint4 m1 = *(const uint4*)(mp + 4);
    const int src = (int)m0.x;
    const int et = (int)(m0.y >> 20);
    const float dtn = __uint_as_float(m0.z);
    const float dss = __uint_as_float(m0.w);
    float aa[8] = { blo(m1.x), bhi(m1.x), blo(m1.y), bhi(m1.y),
                    blo(m1.z), bhi(m1.z), blo(m1.w), bhi(m1.w) };
    const float4 twA = *(const float4*)(tw + c8);
    const float4 twB = *(const float4*)(tw + c8 + 4);
    const float4 tbA = *(const float4*)(tb + c8);
    const float4 tbB = *(const float4*)(tb + c8 + 4);
    const float4 dwA = *(const float4*)(dw + c8);
    const float4 dwB = *(const float4*)(dw + c8 + 4);
    const float4 dbA = *(const float4*)(db + c8);
    const float4 dbB = *(const float4*)(db + c8 + 4);
    const float4 ttA = *(const float4*)(ttab + et * 128 + c8);
    const float4 ttB = *(const float4*)(ttab + et * 128 + c8 + 4);
    float f[8];
    f[0] = __cosf(fmaf(dtn, twA.x, tbA.x)) + __cosf(fmaf(dss, dwA.x, dbA.x)) + ttA.x;
    f[1] = __cosf(fmaf(dtn, twA.y, tbA.y)) + __cosf(fmaf(dss, dwA.y, dbA.y)) + ttA.y;
    f[2] = __cosf(fmaf(dtn, twA.z, tbA.z)) + __cosf(fmaf(dss, dwA.z, dbA.z)) + ttA.z;
    f[3] = __cosf(fmaf(dtn, twA.w, tbA.w)) + __cosf(fmaf(dss, dwA.w, dbA.w)) + ttA.w;
    f[4] = __cosf(fmaf(dtn, twB.x, tbB.x)) + __cosf(fmaf(dss, dwB.x, dbB.x)) + ttB.x;
    f[5] = __cosf(fmaf(dtn, twB.y, tbB.y)) + __cosf(fmaf(dss, dwB.y, dbB.y)) + ttB.y;
    f[6] = __cosf(fmaf(dtn, twB.z, tbB.z)) + __cosf(fmaf(dss, dwB.z, dbB.z)) + ttB.z;
    f[7] = __cosf(fmaf(dtn, twB.w, tbB.w)) + __cosf(fmaf(dss, dwB.w, dbB.w)) + ttB.w;
    #pragma unroll
    for (int a = 0; a < 8; ++a) {
      float4 wA = *(const float4*)(Wa + a * 128 + c8);
      float4 wB = *(const float4*)(Wa + a * 128 + c8 + 4);
      f[0] = fmaf(aa[a], wA.x, f[0]);
      f[1] = fmaf(aa[a], wA.y, f[1]);
      f[2] = fmaf(aa[a], wA.z, f[2]);
      f[3] = fmaf(aa[a], wA.w, f[3]);
      f[4] = fmaf(aa[a], wB.x, f[4]);
      f[5] = fmaf(aa[a], wB.y, f[5]);
      f[6] = fmaf(aa[a], wB.z, f[6]);
      f[7] = fmaf(aa[a], wB.w, f[7]);
    }
    float xv[8];
    if (XF32) {
      float4 xA = *(const float4*)((const float*)xg + (size_t)src * 128 + c8);
      float4 xB = *(const float4*)((const float*)xg + (size_t)src * 128 + c8 + 4);
      xv[0] = xA.x; xv[1] = xA.y; xv[2] = xA.z; xv[3] = xA.w;
      xv[4] = xB.x; xv[5] = xB.y; xv[6] = xB.z; xv[7] = xB.w;
    } else {
      uint4 xr = *(const uint4*)((const u16*)xg + (size_t)src * 128 + c8);
      xv[0] = blo(xr.x); xv[1] = bhi(xr.x); xv[2] = blo(xr.y); xv[3] = bhi(xr.y);
      xv[4] = blo(xr.z); xv[5] = bhi(xr.z); xv[6] = blo(xr.w); xv[7] = bhi(xr.w);
    }
    if (BN) {
      float4 scA = *(const float4*)(scsh + c8);
      float4 scB = *(const float4*)(scsh + c8 + 4);
      float4 shA = *(const float4*)(scsh + 128 + c8);
      float4 shB = *(const float4*)(scsh + 128 + c8 + 4);
      xv[0] = fmaxf(fmaf(xv[0], scA.x, shA.x), 0.f);
      xv[1] = fmaxf(fmaf(xv[1], scA.y, shA.y), 0.f);
      xv[2] = fmaxf(fmaf(xv[2], scA.z, shA.z), 0.f);
      xv[3] = fmaxf(fmaf(xv[3], scA.w, shA.w), 0.f);
      xv[4] = fmaxf(fmaf(xv[4], scB.x, shB.x), 0.f);
      xv[5] = fmaxf(fmaf(xv[5], scB.y, shB.y), 0.f);
      xv[6] = fmaxf(fmaf(xv[6], scB.z, shB.z), 0.f);
      xv[7] = fmaxf(fmaf(xv[7], scB.w, shB.w), 0.f);
    }
    uint4 o;
    o.x = pack2(xv[0] + f[0], xv[1] + f[1]);
    o.y = pack2(xv[2] + f[2], xv[3] + f[3]);
    o.z = pack2(xv[4] + f[4], xv[5] + f[5]);
    o.w = pack2(xv[6] + f[6], xv[7] + f[7]);
    *(uint4*)(kvV + (size_t)e * 128 + c8) = o;
  }
}

// ---------------- edge fused: wave0 = kv-stage + K + logits, wave1 = Q-stage + V ------
// Single tile per block (proven: VGPR 104, no spill, 119 us).

__global__ __launch_bounds__(128, 2)
void edge_kv(const u16* __restrict__ WtK, const u16* __restrict__ WtV,
             const u32* __restrict__ meta, const u16* __restrict__ Qb,
             u16* __restrict__ kvV, float* __restrict__ logits)
{
  __shared__ __align__(16) u16 KVs[4160];  // kv tile
  __shared__ __align__(16) u16 Qs[4160];   // Q[dst] tile; wave1's V C-tile later
  __shared__ int dstSh[32];
  const int t = threadIdx.x;
  const int w = t >> 6, lane = t & 63;
  const int lr = lane & 15, hi = lane >> 4;
  const int e0 = blockIdx.x * 32;
  const u16* Wt = w ? WtV : WtK;

  bf16x8 wt[8][4];
  #pragma unroll
  for (int nb = 0; nb < 8; ++nb)
    #pragma unroll
    for (int ks = 0; ks < 4; ++ks)
      wt[nb][ks] = *(const bf16x8*)(Wt + (nb * 16 + lr) * 128 + ks * 32 + hi * 8);

  if (w == 0) {
    #pragma unroll
    for (int i = 0; i < 8; ++i) {
      int idx = i * 64 + lane;
      int r = idx >> 4, c8 = (idx & 15) << 3;
      uint4 v = *(const uint4*)(kvV + (size_t)(e0 + r) * 128 + c8);
      *(uint4*)(KVs + opsw(r, c8)) = v;
    }
  } else {
    if (lane < 32)
      dstSh[lane] = (int)(meta[(size_t)(e0 + lane) * 8 + 1] & 0xFFFFFu);
    #pragma unroll
    for (int i = 0; i < 8; ++i) {
      int idx = i * 64 + lane;
      int r = idx >> 4, c8 = (idx & 15) << 3;
      int qrow = dstSh[r];
      uint4 qv = *(const uint4*)(Qb + (size_t)qrow * 128 + c8);
      *(uint4*)(Qs + opsw(r, c8)) = qv;
    }
  }
  __syncthreads();

  if (w == 0) {
    #pragma unroll
    for (int eb = 0; eb < 2; ++eb) {
      f32x4 kacc[8];
      #pragma unroll
      for (int b = 0; b < 8; ++b) {
        kacc[b][0] = 0.f; kacc[b][1] = 0.f; kacc[b][2] = 0.f; kacc[b][3] = 0.f;
      }
      #pragma unroll
      for (int ks = 0; ks < 4; ++ks) {
        bf16x8 ef = *(const bf16x8*)(KVs + opsw(eb * 16 + lr, ks * 32 + hi * 8));
        #pragma unroll
        for (int nb = 0; nb < 8; ++nb)
          kacc[nb] = mfma16(wt[nb][ks], ef, kacc[nb]);
      }
      const int el = eb * 16 + lr;
      float hs[4] = {0.f, 0.f, 0.f, 0.f};
      #pragma unroll
      for (int nb = 0; nb < 8; ++nb) {
        ushort4 q = *(const ushort4*)(Qs + opsw(el, nb * 16 + hi * 4));
        hs[nb >> 1] += b2f(q.x) * kacc[nb][0] + b2f(q.y) * kacc[nb][1]
                     + b2f(q.z) * kacc[nb][2] + b2f(q.w) * kacc[nb][3];
      }
      #pragma unroll
      for (int h = 0; h < 4; ++h) {
        hs[h] += __shfl_xor(hs[h], 16, 64);
        hs[h] += __shfl_xor(hs[h], 32, 64);
        hs[h] *= 0.17677669529663687f;                 // 32^-0.5
        hs[h] = (hs[h] >= 0.f) ? hs[h] : 0.2f * hs[h]; // leaky relu
      }
      if (lane < 16)
        *(float4*)(logits + (size_t)(e0 + el) * 4) = make_float4(hs[0], hs[1], hs[2], hs[3]);
    }
    __syncthreads();   // pairs with wave1's barrier: Qs now free for its C tile
  } else {
    f32x4 vacc[2][8];
    #pragma unroll
    for (int a = 0; a < 2; ++a)
      #pragma unroll
      for (int b = 0; b < 8; ++b) {
        vacc[a][b][0] = 0.f; vacc[a][b][1] = 0.f;
        vacc[a][b][2] = 0.f; vacc[a][b][3] = 0.f;
      }
    #pragma unroll
    for (int ks = 0; ks < 4; ++ks) {
      const int kb = ks * 32 + hi * 8;
      bf16x8 a0 = *(const bf16x8*)(KVs + opsw(lr, kb));
      bf16x8 a1 = *(const bf16x8*)(KVs + opsw(16 + lr, kb));
      #pragma unroll
      for (int nb = 0; nb < 8; ++nb) {
        vacc[0][nb] = mfma16(a0, wt[nb][ks], vacc[0][nb]);
        vacc[1][nb] = mfma16(a1, wt[nb][ks], vacc[1][nb]);
      }
    }
    __syncthreads();   // wave0 done reading Qs -> reuse as C tile
    const int g4 = hi << 2;
    #pragma unroll
    for (int mt = 0; mt < 2; ++mt)
      #pragma unroll
      for (int nt = 0; nt < 8; ++nt)
        #pragma unroll
        for (int j = 0; j < 4; ++j)
          Qs[csw(mt * 16 + g4 + j, nt * 16 + lr)] = f2bf(vacc[mt][nt][j]);
    #pragma unroll
    for (int i = 0; i < 8; ++i) {
      int idx = i * 64 + lane;
      int r = idx >> 4, n8 = (idx & 15) << 3;
      uint4 v = *(const uint4*)(Qs + csw(r, n8));
      *(uint4*)(kvV + (size_t)(e0 + r) * 128 + n8) = v;
    }
  }
}

// ---------------- per-node softmax + aggregate + combine + stats ----------------
template<int PREBF16>
__global__ __launch_bounds__(256)
void node_agg(const u16* __restrict__ Vs, const float* __restrict__ logits,
              const int* __restrict__ rowptr, const u16* __restrict__ S,
              const float* __restrict__ betaP, float* __restrict__ pre,
              u16* __restrict__ preb, float* __restrict__ colsum,
              float* __restrict__ colsumsq)
{
  __shared__ float red[1024];
  const int t = threadIdx.x;
  const int g = t >> 5;
  const int lane = t & 31;
  const int d0 = lane * 4;
  const int h = lane >> 3;
  const float beta = *betaP;
  const float omb = 1.f - beta;
  float s4[4] = {0.f, 0.f, 0.f, 0.f};
  float q4[4] = {0.f, 0.f, 0.f, 0.f};
  for (int rep = 0; rep < 16; ++rep) {
    int n = blockIdx.x * 128 + rep * 8 + g;
    if (n < N_NODES) {
      int rs = rowptr[n], re = rowptr[n + 1];
      float m = -1e30f;
      for (int i = rs; i < re; ++i)
        m = fmaxf(m, logits[(size_t)i * 4 + h]);
      float den = 0.f;
      float a0 = 0.f, a1 = 0.f, a2 = 0.f, a3 = 0.f;
      for (int i = rs; i < re; ++i) {
        float wgt = __expf(logits[(size_t)i * 4 + h] - m);
        den += wgt;
        ushort4 v = *(const ushort4*)(Vs + (size_t)i * 128 + d0);
        a0 = fmaf(wgt, b2f(v.x), a0);
        a1 = fmaf(wgt, b2f(v.y), a1);
        a2 = fmaf(wgt, b2f(v.z), a2);
        a3 = fmaf(wgt, b2f(v.w), a3);
      }
      float inv = (den > 0.f) ? (omb / den) : 0.f;
      ushort4 sv = *(const ushort4*)(S + (size_t)n * 128 + d0);
      float p0 = fmaf(beta, b2f(sv.x), a0 * inv);
      float p1 = fmaf(beta, b2f(sv.y), a1 * inv);
      float p2 = fmaf(beta, b2f(sv.z), a2 * inv);
      float p3 = fmaf(beta, b2f(sv.w), a3 * inv);
      if (PREBF16) {
        ushort4 o;
        o.x = f2bf(p0); o.y = f2bf(p1); o.z = f2bf(p2); o.w = f2bf(p3);
        *(ushort4*)(preb + (size_t)n * 128 + d0) = o;
      } else {
        *(float4*)(pre + (size_t)n * 128 + d0) = make_float4(p0, p1, p2, p3);
      }
      s4[0] += p0; s4[1] += p1; s4[2] += p2; s4[3] += p3;
      q4[0] += p0 * p0; q4[1] += p1 * p1; q4[2] += p2 * p2; q4[3] += p3 * p3;
    }
  }
  *(float4*)(&red[g * 128 + d0]) = make_float4(s4[0], s4[1], s4[2], s4[3]);
  __syncthreads();
  if (t < 128) {
    float tot = 0.f;
    #pragma unroll
    for (int gg = 0; gg < 8; ++gg) tot += red[gg * 128 + t];
    atomicAdd(&colsum[t], tot);
  }
  __syncthreads();
  *(float4*)(&red[g * 128 + d0]) = make_float4(q4[0], q4[1], q4[2], q4[3]);
  __syncthreads();
  if (t < 128) {
    float tot = 0.f;
    #pragma unroll
    for (int gg = 0; gg < 8; ++gg) tot += red[gg * 128 + t];
    atomicAdd(&colsumsq[t], tot);
  }
}

// ---------------- BatchNorm + ReLU for the LAST layer (f32 in d_out) ----------------
__global__ __launch_bounds__(256)
void bn_apply(const float* __restrict__ pre, const float* __restrict__ colsum,
              const float* __restrict__ colsumsq, const float* __restrict__ gamma,
              const float* __restrict__ bvec, float* __restrict__ outf)
{
  const int idx = blockIdx.x * 256 + threadIdx.x;
  const int n = idx >> 5;
  const int d0 = (idx & 31) * 4;
  const float invN = 1.f / 150000.f;
  float4 p = *(const float4*)(pre + (size_t)n * 128 + d0);
  float4 cs = *(const float4*)(colsum + d0);
  float4 cq = *(const float4*)(colsumsq + d0);
  float4 gm = *(const float4*)(gamma + d0);
  float4 bv = *(const float4*)(bvec + d0);
  float mu, var, y;
  mu = cs.x * invN; var = cq.x * invN - mu * mu;
  y = (p.x - mu) * rsqrtf(var + 1e-5f) * gm.x + bv.x; p.x = fmaxf(y, 0.f);
  mu = cs.y * invN; var = cq.y * invN - mu * mu;
  y = (p.y - mu) * rsqrtf(var + 1e-5f) * gm.y + bv.y; p.y = fmaxf(y, 0.f);
  mu = cs.z * invN; var = cq.z * invN - mu * mu;
  y = (p.z - mu) * rsqrtf(var + 1e-5f) * gm.z + bv.z; p.z = fmaxf(y, 0.f);
  mu = cs.w * invN; var = cq.w * invN - mu * mu;
  y = (p.w - mu) * rsqrtf(var + 1e-5f) * gm.w + bv.w; p.w = fmaxf(y, 0.f);
  *(float4*)(outf + (size_t)n * 128 + d0) = p;
}

extern "C" void kernel_launch(void* const* d_in, const int* in_sizes, int n_in,
                              void* d_out, int out_size, void* d_ws, size_t ws_size,
                              hipStream_t stream)
{
  const float* x0    = (const float*)d_in[0];
  const float* Wq    = (const float*)d_in[1];
  const float* Wk    = (const float*)d_in[2];
  const float* Wv    = (const float*)d_in[3];
  const float* Wsk   = (const float*)d_in[4];
  const float* Wa    = (const float*)d_in[5];
  const float* tw    = (const float*)d_in[6];
  const float* tb    = (const float*)d_in[7];
  const float* dw    = (const float*)d_in[8];
  const float* db    = (const float*)d_in[9];
  const float* ttab  = (const float*)d_in[10];
  const float* gam   = (const float*)d_in[11];
  const float* bet   = (const float*)d_in[12];
  const float* betaP = (const float*)d_in[13];
  const float* attr  = (const float*)d_in[14];
  const float* dt    = (const float*)d_in[15];
  const float* dsv   = (const float*)d_in[16];
  const int*   eidx  = (const int*)d_in[17];
  const int*   etyp  = (const int*)d_in[18];

  // workspace ~212 MB
  char* p = (char*)d_ws;
  u16* xbf  = (u16*)p;       p += 38400000;          // [N,128] bf16: pre of previous layer
  u16* Q    = (u16*)p;       p += 38400000;          // [N,128] bf16
  u16* S    = (u16*)p;       p += 38400000;          // [N,128] bf16
  u16* kvV  = (u16*)p;       p += 76800000;          // [E,128] bf16: kv_in, then V (in place)
  float* logits = (float*)p; p += 4800000;           // [E,4] f32 dst-sorted
  int* rowptr = (int*)p;     p += 4 * L_CNT * 4;
  int* tmp    = (int*)p;     p += 4 * L_CNT * 4;
  int* bsum   = (int*)p;     p += 4 * 128 * 4;
  float* colsum   = (float*)p; p += 512;
  float* colsumsq = (float*)p; p += 512;
  float* scsh     = (float*)p; p += 1024;            // {scale[128], shift[128]}
  u16* Wt = (u16*)p;         p += 16 * 16384 * 2;    // 16 transposed bf16 weights
  u32* meta = (u32*)p;       p += (size_t)E_EDGES * 32;  // 32B/edge, per-layer reuse

  float* pre = (float*)d_out;   // [N,128] f32 scratch for LAST layer

  // weight transpose + CSR build (once)
  k_wt<<<16, 256, 0, stream>>>(Wq, Wk, Wv, Wsk, Wt);
  hipMemsetAsync(tmp, 0, 4 * L_CNT * 4, stream);
  k_hist<<<dim3(1172, 4), 256, 0, stream>>>(eidx, tmp);
  k_scan1<<<dim3(74, 4), 256, 0, stream>>>(tmp, rowptr, bsum);
  k_scan2<<<4, 128, 0, stream>>>(bsum);
  k_scan3<<<dim3(592, 4), 256, 0, stream>>>(rowptr, tmp, bsum);

  for (int l = 0; l < 4; ++l) {
    const int* srcA = eidx + (size_t)l * 600000;
    const int* dstA = srcA + 300000;
    const int* rpl = rowptr + (size_t)l * L_CNT;
    const u16* WtQl = Wt + (size_t)l * 16384;
    const u16* WtKl = Wt + (size_t)(4 + l) * 16384;
    const u16* WtVl = Wt + (size_t)(8 + l) * 16384;
    const u16* WtSl = Wt + (size_t)(12 + l) * 16384;
    const float* Wal = Wa + (size_t)l * 1024;

    k_scatter<<<1172, 256, 0, stream>>>(
        srcA, dstA, etyp + (size_t)l * 300000, dt + (size_t)l * 300000,
        dsv + (size_t)l * 300000, attr + (size_t)l * 2400000,
        tmp + (size_t)l * L_CNT, meta);

    hipMemsetAsync(colsum, 0, 1024, stream);

    if (l == 0) {
      prep<1, 0><<<NTILES + KVBLKS, 128, 0, stream>>>(
          (const void*)x0, WtQl, WtSl, scsh, Q, S,
          Wal, tw, tb, dw, db, ttab, meta, kvV);
    } else {
      prep<0, 1><<<NTILES + KVBLKS, 128, 0, stream>>>(
          (const void*)xbf, WtQl, WtSl, scsh, Q, S,
          Wal, tw, tb, dw, db, ttab, meta, kvV);
    }

    edge_kv<<<ETILES, 128, 0, stream>>>(WtKl, WtVl, meta, Q, kvV, logits);

    if (l < 3) {
      node_agg<1><<<1172, 256, 0, stream>>>(kvV, logits, rpl, S, betaP + l,
                                            nullptr, xbf, colsum, colsumsq);
      bn_stats<<<1, 128, 0, stream>>>(colsum, colsumsq, gam + (size_t)l * 128,
                                      bet + (size_t)l * 128, scsh);
    } else {
      node_agg<0><<<1172, 256, 0, stream>>>(kvV, logits, rpl, S, betaP + l,
                                            pre, nullptr, colsum, colsumsq);
      bn_apply<<<18750, 256, 0, stream>>>(pre, colsum, colsumsq,
                                          gam + (size_t)l * 128,
                                          bet + (size_t)l * 128, (float*)d_out);
    }
  }
}

// Round 22
// 1415.540 us; speedup vs baseline: 1.0156x; 1.0082x over previous
//
#include <hip/hip_runtime.h>

typedef unsigned int u32;
typedef unsigned short u16;
typedef short bf16x8 __attribute__((ext_vector_type(8)));
typedef float f32x4 __attribute__((ext_vector_type(4)));

#define N_NODES 150000
#define E_EDGES 300000
#define L_CNT   151552   // 74*2048 padded per-layer node stride
#define ETILES  9375     // E/32
#define NTILES  4688     // ceil(N/32)
#define KVBLKS  37500    // E*16/128 chunks at 128 threads
#define AGGB    1172     // node_agg blocks
#define SCATB   1172     // scatter blocks (E/256)

__device__ __forceinline__ float blo(u32 u){ return __uint_as_float(u << 16); }
__device__ __forceinline__ float bhi(u32 u){ return __uint_as_float(u & 0xffff0000u); }
__device__ __forceinline__ float b2f(u16 h){ return __uint_as_float(((u32)h) << 16); }
__device__ __forceinline__ u16 f2bf(float f){
  u32 u = __float_as_uint(f);
  return (u16)((u + 0x7fffu + ((u >> 16) & 1u)) >> 16);   // RNE
}
__device__ __forceinline__ u32 pack2(float a, float b){
  return (u32)f2bf(a) | ((u32)f2bf(b) << 16);
}

__device__ __forceinline__ f32x4 mfma16(bf16x8 a, bf16x8 b, f32x4 c){
  return __builtin_amdgcn_mfma_f32_16x16x32_bf16(a, b, c, 0, 0, 0);
}

// operand tile [r=0..31][k=0..127] u16, XOR-swizzled
__device__ __forceinline__ int opsw(int r, int k){ return (r * 128 + k) ^ ((r & 7) << 3); }
// C tile [r][n] swizzle
__device__ __forceinline__ int csw(int r, int n){ return (r * 128 + n) ^ (((r >> 2) & 3) << 3); }

// ---------------- weight pre-transpose: Wt[n][k] bf16 <- W[k][n] f32 ----------------
__global__ __launch_bounds__(256)
void k_wt(const float* __restrict__ Wq, const float* __restrict__ Wk,
          const float* __restrict__ Wv, const float* __restrict__ Ws,
          u16* __restrict__ Wt)
{
  const int m = blockIdx.x;   // 0..15: [Wq0-3, Wk0-3, Wv0-3, Wsk0-3]
  const float* src = (m < 4 ? Wq : m < 8 ? Wk : m < 12 ? Wv : Ws)
                     + (size_t)(m & 3) * 16384;
  u16* dst = Wt + (size_t)m * 16384;
  const int t = threadIdx.x;
  for (int i = 0; i < 16; ++i) {
    int idx = i * 256 + t;
    int n = idx >> 5;
    int k4 = (idx & 31) << 2;
    ushort4 o;
    o.x = f2bf(src[(k4 + 0) * 128 + n]);
    o.y = f2bf(src[(k4 + 1) * 128 + n]);
    o.z = f2bf(src[(k4 + 2) * 128 + n]);
    o.w = f2bf(src[(k4 + 3) * 128 + n]);
    *(ushort4*)(dst + n * 128 + k4) = o;
  }
}

// ---------------- CSR build (counting sort of edges by dst) ----------------

__global__ __launch_bounds__(256)
void k_hist(const int* __restrict__ eidx, int* __restrict__ counts)
{
  const int l = blockIdx.y;
  const int e = blockIdx.x * 256 + threadIdx.x;
  if (e < E_EDGES) {
    int dst = eidx[(size_t)l * 2 * E_EDGES + E_EDGES + e];
    atomicAdd(&counts[(size_t)l * L_CNT + dst], 1);
  }
}

__global__ __launch_bounds__(256)
void k_scan1(const int* __restrict__ counts, int* __restrict__ rowptr,
             int* __restrict__ bsum)
{
  __shared__ int sh[256];
  const int b = blockIdx.x, l = blockIdx.y;
  const int t = threadIdx.x;
  const int* c = counts + (size_t)l * L_CNT + b * 2048;
  int* rp = rowptr + (size_t)l * L_CNT + b * 2048;
  int v[8]; int s = 0;
  #pragma unroll
  for (int j = 0; j < 8; ++j) { v[j] = c[t * 8 + j]; s += v[j]; }
  sh[t] = s; __syncthreads();
  for (int off = 1; off < 256; off <<= 1) {
    int x = (t >= off) ? sh[t - off] : 0;
    __syncthreads();
    sh[t] += x;
    __syncthreads();
  }
  int excl = (t == 0) ? 0 : sh[t - 1];
  if (t == 255) bsum[l * 128 + b] = sh[255];
  int run = excl;
  #pragma unroll
  for (int j = 0; j < 8; ++j) { rp[t * 8 + j] = run; run += v[j]; }
}

__global__ __launch_bounds__(128)
void k_scan2(int* __restrict__ bsum)
{
  __shared__ int sh[128];
  const int l = blockIdx.x, t = threadIdx.x;
  int v = (t < 74) ? bsum[l * 128 + t] : 0;
  sh[t] = v; __syncthreads();
  for (int off = 1; off < 128; off <<= 1) {
    int x = (t >= off) ? sh[t - off] : 0;
    __syncthreads();
    sh[t] += x;
    __syncthreads();
  }
  int excl = (t == 0) ? 0 : sh[t - 1];
  if (t < 74) bsum[l * 128 + t] = excl;
}

__global__ __launch_bounds__(256)
void k_scan3(int* __restrict__ rowptr, int* __restrict__ tmp,
             const int* __restrict__ bsum)
{
  const int l = blockIdx.y;
  const int q = blockIdx.x * 256 + threadIdx.x;
  int v = rowptr[(size_t)l * L_CNT + q] + bsum[l * 128 + (q >> 11)];
  rowptr[(size_t)l * L_CNT + q] = v;
  tmp[(size_t)l * L_CNT + q] = v;
}

// scatter device body: edge e -> dst-sorted 32B meta record
// r0 = {src, dst | et<<20, dt/24, ds}; r1 = attr as bf16x8.
__device__ __forceinline__ void scatter_one(
    int e, const int* __restrict__ srcP, const int* __restrict__ dstP,
    const int* __restrict__ etP, const float* __restrict__ dtP,
    const float* __restrict__ dsP, const float* __restrict__ attrP,
    int* __restrict__ tmpL, u32* __restrict__ meta)
{
  int dst = dstP[e];
  int pos = atomicAdd(&tmpL[dst], 1);
  int src = srcP[e];
  int et  = etP[e];
  float dtn = dtP[e] * (1.0f / 24.0f);
  float dsv = dsP[e];
  float4 aA = *(const float4*)(attrP + (size_t)e * 8);
  float4 aB = *(const float4*)(attrP + (size_t)e * 8 + 4);
  uint4 r0, r1;
  r0.x = (u32)src;
  r0.y = (u32)dst | ((u32)et << 20);
  r0.z = __float_as_uint(dtn);
  r0.w = __float_as_uint(dsv);
  r1.x = pack2(aA.x, aA.y); r1.y = pack2(aA.z, aA.w);
  r1.z = pack2(aB.x, aB.y); r1.w = pack2(aB.z, aB.w);
  u32* mp = meta + (size_t)pos * 8;
  *(uint4*)mp = r0;
  *(uint4*)(mp + 4) = r1;
}

__global__ __launch_bounds__(256)
void k_scatter(const int* __restrict__ srcP, const int* __restrict__ dstP,
               const int* __restrict__ etP, const float* __restrict__ dtP,
               const float* __restrict__ dsP, const float* __restrict__ attrP,
               int* __restrict__ tmpL, u32* __restrict__ meta)
{
  const int e = blockIdx.x * 256 + threadIdx.x;
  if (e < E_EDGES)
    scatter_one(e, srcP, dstP, etP, dtP, dsP, attrP, tmpL, meta);
}

// ---------------- BN stats fold: scsh = {scale[128], shift[128]} ----------------
__global__ __launch_bounds__(128)
void bn_stats(const float* __restrict__ colsum, const float* __restrict__ colsumsq,
              const float* __restrict__ gamma, const float* __restrict__ bvec,
              float* __restrict__ scsh)
{
  const int d = threadIdx.x;
  const float invN = 1.f / 150000.f;
  float mu = colsum[d] * invN;
  float var = colsumsq[d] * invN - mu * mu;
  float sc = gamma[d] * rsqrtf(var + 1e-5f);
  scsh[d] = sc;
  scsh[128 + d] = bvec[d] - mu * sc;
}

// ---------------- combined prep: gemm_qs blocks + kv_in blocks in ONE launch ----------
// blockIdx.x < NTILES : node GEMM tile (wave0 -> Q, wave1 -> S), proven body.
// blockIdx.x >= NTILES: kv_in feature chunks (128 threads), proven body.

template<int XF32, int BN>
__global__ __launch_bounds__(128, 2)
void prep(const void* __restrict__ xg, const u16* __restrict__ WtQ,
          const u16* __restrict__ WtS, const float* __restrict__ scsh,
          u16* __restrict__ Qo, u16* __restrict__ So,
          const float* __restrict__ Wa, const float* __restrict__ tw,
          const float* __restrict__ tb, const float* __restrict__ dw,
          const float* __restrict__ db, const float* __restrict__ ttab,
          const u32* __restrict__ meta, u16* __restrict__ kvV)
{
  __shared__ __align__(16) u16 As[4160];
  __shared__ __align__(16) u16 Bs[4160];
  const int t = threadIdx.x;

  if (blockIdx.x < NTILES) {
    // ---------------- node GEMM path ----------------
    const int w = t >> 6, lane = t & 63;
    const int lr = lane & 15, hi = lane >> 4;
    const int row0 = blockIdx.x * 32;
    const int nr = min(32, N_NODES - row0);
    const u16* Wt = w ? WtS : WtQ;
    u16* C = w ? So : Qo;

    bf16x8 wt[8][4];
    #pragma unroll
    for (int nb = 0; nb < 8; ++nb)
      #pragma unroll
      for (int ks = 0; ks < 4; ++ks)
        wt[nb][ks] = *(const bf16x8*)(Wt + (nb * 16 + lr) * 128 + ks * 32 + hi * 8);

    #pragma unroll
    for (int i = 0; i < 4; ++i) {
      int idx = i * 128 + t;
      int r = idx >> 4, c8 = (idx & 15) << 3;
      if (r < nr) {
        if (XF32) {
          float4 vA = *(const float4*)((const float*)xg + (size_t)(row0 + r) * 128 + c8);
          float4 vB = *(const float4*)((const float*)xg + (size_t)(row0 + r) * 128 + c8 + 4);
          uint4 o;
          o.x = pack2(vA.x, vA.y); o.y = pack2(vA.z, vA.w);
          o.z = pack2(vB.x, vB.y); o.w = pack2(vB.z, vB.w);
          *(uint4*)(As + opsw(r, c8)) = o;
        } else {
          uint4 v = *(const uint4*)((const u16*)xg + (size_t)(row0 + r) * 128 + c8);
          if (BN) {
            float4 scA = *(const float4*)(scsh + c8);
            float4 scB = *(const float4*)(scsh + c8 + 4);
            float4 shA = *(const float4*)(scsh + 128 + c8);
            float4 shB = *(const float4*)(scsh + 128 + c8 + 4);
            float e0v = fmaxf(fmaf(blo(v.x), scA.x, shA.x), 0.f);
            float e1v = fmaxf(fmaf(bhi(v.x), scA.y, shA.y), 0.f);
            float e2v = fmaxf(fmaf(blo(v.y), scA.z, shA.z), 0.f);
            float e3v = fmaxf(fmaf(bhi(v.y), scA.w, shA.w), 0.f);
            float e4v = fmaxf(fmaf(blo(v.z), scB.x, shB.x), 0.f);
            float e5v = fmaxf(fmaf(bhi(v.z), scB.y, shB.y), 0.f);
            float e6v = fmaxf(fmaf(blo(v.w), scB.z, shB.z), 0.f);
            float e7v = fmaxf(fmaf(bhi(v.w), scB.w, shB.w), 0.f);
            v.x = pack2(e0v, e1v); v.y = pack2(e2v, e3v);
            v.z = pack2(e4v, e5v); v.w = pack2(e6v, e7v);
          }
          *(uint4*)(As + opsw(r, c8)) = v;
        }
      } else {
        *(uint4*)(As + opsw(r, c8)) = make_uint4(0, 0, 0, 0);
      }
    }
    __syncthreads();

    f32x4 acc[2][8];
    #pragma unroll
    for (int a = 0; a < 2; ++a)
      #pragma unroll
      for (int b = 0; b < 8; ++b) {
        acc[a][b][0] = 0.f; acc[a][b][1] = 0.f;
        acc[a][b][2] = 0.f; acc[a][b][3] = 0.f;
      }
    #pragma unroll
    for (int ks = 0; ks < 4; ++ks) {
      const int kb = ks * 32 + hi * 8;
      bf16x8 a0 = *(const bf16x8*)(As + opsw(lr, kb));
      bf16x8 a1 = *(const bf16x8*)(As + opsw(16 + lr, kb));
      #pragma unroll
      for (int nb = 0; nb < 8; ++nb) {
        acc[0][nb] = mfma16(a0, wt[nb][ks], acc[0][nb]);
        acc[1][nb] = mfma16(a1, wt[nb][ks], acc[1][nb]);
      }
    }
    __syncthreads();   // all As reads complete before wave0 overwrites it

    u16* Cs = w ? Bs : As;
    const int g4 = hi << 2;
    #pragma unroll
    for (int mt = 0; mt < 2; ++mt)
      #pragma unroll
      for (int nt = 0; nt < 8; ++nt)
        #pragma unroll
        for (int j = 0; j < 4; ++j)
          Cs[csw(mt * 16 + g4 + j, nt * 16 + lr)] = f2bf(acc[mt][nt][j]);
    #pragma unroll
    for (int i = 0; i < 8; ++i) {
      int idx = i * 64 + lane;
      int r = idx >> 4, n8 = (idx & 15) << 3;
      if (r < nr) {
        uint4 v = *(const uint4*)(Cs + csw(r, n8));
        *(uint4*)(C + (size_t)(row0 + r) * 128 + n8) = v;
      }
    }
  } else {
    // ---------------- kv_in path (one 8-dim chunk per thread) ----------------
    const int idx = (blockIdx.x - NTILES) * 128 + t;   // E*16 chunks
    const int e = idx >> 4;
    const int c8 = (idx & 15) << 3;
    const u32* mp = meta + (size_t)e * 8;
    uint4 m0 = *(const uint4*)mp;
    uint4 m1 = *(const uint4*)(mp + 4);
    const int src = (int)m0.x;
    const int et = (int)(m0.y >> 20);
    const float dtn = __uint_as_float(m0.z);
    const float dss = __uint_as_float(m0.w);
    float aa[8] = { blo(m1.x), bhi(m1.x), blo(m1.y), bhi(m1.y),
                    blo(m1.z), bhi(m1.z), blo(m1.w), bhi(m1.w) };
    const float4 twA = *(const float4*)(tw + c8);
    const float4 twB = *(const float4*)(tw + c8 + 4);
    const float4 tbA = *(const float4*)(tb + c8);
    const float4 tbB = *(const float4*)(tb + c8 + 4);
    const float4 dwA = *(const float4*)(dw + c8);
    const float4 dwB = *(const float4*)(dw + c8 + 4);
    const float4 dbA = *(const float4*)(db + c8);
    const float4 dbB = *(const float4*)(db + c8 + 4);
    const float4 ttA = *(const float4*)(ttab + et * 128 + c8);
    const float4 ttB = *(const float4*)(ttab + et * 128 + c8 + 4);
    float f[8];
    f[0] = __cosf(fmaf(dtn, twA.x, tbA.x)) + __cosf(fmaf(dss, dwA.x, dbA.x)) + ttA.x;
    f[1] = __cosf(fmaf(dtn, twA.y, tbA.y)) + __cosf(fmaf(dss, dwA.y, dbA.y)) + ttA.y;
    f[2] = __cosf(fmaf(dtn, twA.z, tbA.z)) + __cosf(fmaf(dss, dwA.z, dbA.z)) + ttA.z;
    f[3] = __cosf(fmaf(dtn, twA.w, tbA.w)) + __cosf(fmaf(dss, dwA.w, dbA.w)) + ttA.w;
    f[4] = __cosf(fmaf(dtn, twB.x, tbB.x)) + __cosf(fmaf(dss, dwB.x, dbB.x)) + ttB.x;
    f[5] = __cosf(fmaf(dtn, twB.y, tbB.y)) + __cosf(fmaf(dss, dwB.y, dbB.y)) + ttB.y;
    f[6] = __cosf(fmaf(dtn, twB.z, tbB.z)) + __cosf(fmaf(dss, dwB.z, dbB.z)) + ttB.z;
    f[7] = __cosf(fmaf(dtn, twB.w, tbB.w)) + __cosf(fmaf(dss, dwB.w, dbB.w)) + ttB.w;
    #pragma unroll
    for (int a = 0; a < 8; ++a) {
      float4 wA = *(const float4*)(Wa + a * 128 + c8);
      float4 wB = *(const float4*)(Wa + a * 128 + c8 + 4);
      f[0] = fmaf(aa[a], wA.x, f[0]);
      f[1] = fmaf(aa[a], wA.y, f[1]);
      f[2] = fmaf(aa[a], wA.z, f[2]);
      f[3] = fmaf(aa[a], wA.w, f[3]);
      f[4] = fmaf(aa[a], wB.x, f[4]);
      f[5] = fmaf(aa[a], wB.y, f[5]);
      f[6] = fmaf(aa[a], wB.z, f[6]);
      f[7] = fmaf(aa[a], wB.w, f[7]);
    }
    float xv[8];
    if (XF32) {
      float4 xA = *(const float4*)((const float*)xg + (size_t)src * 128 + c8);
      float4 xB = *(const float4*)((const float*)xg + (size_t)src * 128 + c8 + 4);
      xv[0] = xA.x; xv[1] = xA.y; xv[2] = xA.z; xv[3] = xA.w;
      xv[4] = xB.x; xv[5] = xB.y; xv[6] = xB.z; xv[7] = xB.w;
    } else {
      uint4 xr = *(const uint4*)((const u16*)xg + (size_t)src * 128 + c8);
      xv[0] = blo(xr.x); xv[1] = bhi(xr.x); xv[2] = blo(xr.y); xv[3] = bhi(xr.y);
      xv[4] = blo(xr.z); xv[5] = bhi(xr.z); xv[6] = blo(xr.w); xv[7] = bhi(xr.w);
    }
    if (BN) {
      float4 scA = *(const float4*)(scsh + c8);
      float4 scB = *(const float4*)(scsh + c8 + 4);
      float4 shA = *(const float4*)(scsh + 128 + c8);
      float4 shB = *(const float4*)(scsh + 128 + c8 + 4);
      xv[0] = fmaxf(fmaf(xv[0], scA.x, shA.x), 0.f);
      xv[1] = fmaxf(fmaf(xv[1], scA.y, shA.y), 0.f);
      xv[2] = fmaxf(fmaf(xv[2], scA.z, shA.z), 0.f);
      xv[3] = fmaxf(fmaf(xv[3], scA.w, shA.w), 0.f);
      xv[4] = fmaxf(fmaf(xv[4], scB.x, shB.x), 0.f);
      xv[5] = fmaxf(fmaf(xv[5], scB.y, shB.y), 0.f);
      xv[6] = fmaxf(fmaf(xv[6], scB.z, shB.z), 0.f);
      xv[7] = fmaxf(fmaf(xv[7], scB.w, shB.w), 0.f);
    }
    uint4 o;
    o.x = pack2(xv[0] + f[0], xv[1] + f[1]);
    o.y = pack2(xv[2] + f[2], xv[3] + f[3]);
    o.z = pack2(xv[4] + f[4], xv[5] + f[5]);
    o.w = pack2(xv[6] + f[6], xv[7] + f[7]);
    *(uint4*)(kvV + (size_t)e * 128 + c8) = o;
  }
}

// ---------------- edge fused: wave0 = kv-stage + K + logits, wave1 = Q-stage + V ------
// Single tile per block (proven: VGPR 104, no spill, 119 us).

__global__ __launch_bounds__(128, 2)
void edge_kv(const u16* __restrict__ WtK, const u16* __restrict__ WtV,
             const u32* __restrict__ meta, const u16* __restrict__ Qb,
             u16* __restrict__ kvV, float* __restrict__ logits)
{
  __shared__ __align__(16) u16 KVs[4160];  // kv tile
  __shared__ __align__(16) u16 Qs[4160];   // Q[dst] tile; wave1's V C-tile later
  __shared__ int dstSh[32];
  const int t = threadIdx.x;
  const int w = t >> 6, lane = t & 63;
  const int lr = lane & 15, hi = lane >> 4;
  const int e0 = blockIdx.x * 32;
  const u16* Wt = w ? WtV : WtK;

  bf16x8 wt[8][4];
  #pragma unroll
  for (int nb = 0; nb < 8; ++nb)
    #pragma unroll
    for (int ks = 0; ks < 4; ++ks)
      wt[nb][ks] = *(const bf16x8*)(Wt + (nb * 16 + lr) * 128 + ks * 32 + hi * 8);

  if (w == 0) {
    #pragma unroll
    for (int i = 0; i < 8; ++i) {
      int idx = i * 64 + lane;
      int r = idx >> 4, c8 = (idx & 15) << 3;
      uint4 v = *(const uint4*)(kvV + (size_t)(e0 + r) * 128 + c8);
      *(uint4*)(KVs + opsw(r, c8)) = v;
    }
  } else {
    if (lane < 32)
      dstSh[lane] = (int)(meta[(size_t)(e0 + lane) * 8 + 1] & 0xFFFFFu);
    #pragma unroll
    for (int i = 0; i < 8; ++i) {
      int idx = i * 64 + lane;
      int r = idx >> 4, c8 = (idx & 15) << 3;
      int qrow = dstSh[r];
      uint4 qv = *(const uint4*)(Qb + (size_t)qrow * 128 + c8);
      *(uint4*)(Qs + opsw(r, c8)) = qv;
    }
  }
  __syncthreads();

  if (w == 0) {
    #pragma unroll
    for (int eb = 0; eb < 2; ++eb) {
      f32x4 kacc[8];
      #pragma unroll
      for (int b = 0; b < 8; ++b) {
        kacc[b][0] = 0.f; kacc[b][1] = 0.f; kacc[b][2] = 0.f; kacc[b][3] = 0.f;
      }
      #pragma unroll
      for (int ks = 0; ks < 4; ++ks) {
        bf16x8 ef = *(const bf16x8*)(KVs + opsw(eb * 16 + lr, ks * 32 + hi * 8));
        #pragma unroll
        for (int nb = 0; nb < 8; ++nb)
          kacc[nb] = mfma16(wt[nb][ks], ef, kacc[nb]);
      }
      const int el = eb * 16 + lr;
      float hs[4] = {0.f, 0.f, 0.f, 0.f};
      #pragma unroll
      for (int nb = 0; nb < 8; ++nb) {
        ushort4 q = *(const ushort4*)(Qs + opsw(el, nb * 16 + hi * 4));
        hs[nb >> 1] += b2f(q.x) * kacc[nb][0] + b2f(q.y) * kacc[nb][1]
                     + b2f(q.z) * kacc[nb][2] + b2f(q.w) * kacc[nb][3];
      }
      #pragma unroll
      for (int h = 0; h < 4; ++h) {
        hs[h] += __shfl_xor(hs[h], 16, 64);
        hs[h] += __shfl_xor(hs[h], 32, 64);
        hs[h] *= 0.17677669529663687f;                 // 32^-0.5
        hs[h] = (hs[h] >= 0.f) ? hs[h] : 0.2f * hs[h]; // leaky relu
      }
      if (lane < 16)
        *(float4*)(logits + (size_t)(e0 + el) * 4) = make_float4(hs[0], hs[1], hs[2], hs[3]);
    }
    __syncthreads();   // pairs with wave1's barrier: Qs now free for its C tile
  } else {
    f32x4 vacc[2][8];
    #pragma unroll
    for (int a = 0; a < 2; ++a)
      #pragma unroll
      for (int b = 0; b < 8; ++b) {
        vacc[a][b][0] = 0.f; vacc[a][b][1] = 0.f;
        vacc[a][b][2] = 0.f; vacc[a][b][3] = 0.f;
      }
    #pragma unroll
    for (int ks = 0; ks < 4; ++ks) {
      const int kb = ks * 32 + hi * 8;
      bf16x8 a0 = *(const bf16x8*)(KVs + opsw(lr, kb));
      bf16x8 a1 = *(const bf16x8*)(KVs + opsw(16 + lr, kb));
      #pragma unroll
      for (int nb = 0; nb < 8; ++nb) {
        vacc[0][nb] = mfma16(a0, wt[nb][ks], vacc[0][nb]);
        vacc[1][nb] = mfma16(a1, wt[nb][ks], vacc[1][nb]);
      }
    }
    __syncthreads();   // wave0 done reading Qs -> reuse as C tile
    const int g4 = hi << 2;
    #pragma unroll
    for (int mt = 0; mt < 2; ++mt)
      #pragma unroll
      for (int nt = 0; nt < 8; ++nt)
        #pragma unroll
        for (int j = 0; j < 4; ++j)
          Qs[csw(mt * 16 + g4 + j, nt * 16 + lr)] = f2bf(vacc[mt][nt][j]);
    #pragma unroll
    for (int i = 0; i < 8; ++i) {
      int idx = i * 64 + lane;
      int r = idx >> 4, n8 = (idx & 15) << 3;
      uint4 v = *(const uint4*)(Qs + csw(r, n8));
      *(uint4*)(kvV + (size_t)(e0 + r) * 128 + n8) = v;
    }
  }
}

// ---------------- per-node softmax + aggregate + combine + stats ----------------
// blockIdx.x >= AGGB: next-layer scatter blocks (metaN != nullptr only for l<3).
template<int PREBF16>
__global__ __launch_bounds__(256)
void node_agg(const u16* __restrict__ Vs, const float* __restrict__ logits,
              const int* __restrict__ rowptr, const u16* __restrict__ S,
              const float* __restrict__ betaP, float* __restrict__ pre,
              u16* __restrict__ preb, float* __restrict__ colsum,
              float* __restrict__ colsumsq,
              const int* __restrict__ srcN, const int* __restrict__ dstN,
              const int* __restrict__ etN, const float* __restrict__ dtN,
              const float* __restrict__ dsN, const float* __restrict__ attrN,
              int* __restrict__ tmpN, u32* __restrict__ metaN)
{
  if (blockIdx.x >= AGGB) {
    int e = (int)(blockIdx.x - AGGB) * 256 + threadIdx.x;
    if (metaN != nullptr && e < E_EDGES)
      scatter_one(e, srcN, dstN, etN, dtN, dsN, attrN, tmpN, metaN);
    return;
  }

  __shared__ float red[1024];
  const int t = threadIdx.x;
  const int g = t >> 5;
  const int lane = t & 31;
  const int d0 = lane * 4;
  const int h = lane >> 3;
  const float beta = *betaP;
  const float omb = 1.f - beta;
  float s4[4] = {0.f, 0.f, 0.f, 0.f};
  float q4[4] = {0.f, 0.f, 0.f, 0.f};
  for (int rep = 0; rep < 16; ++rep) {
    int n = blockIdx.x * 128 + rep * 8 + g;
    if (n < N_NODES) {
      int rs = rowptr[n], re = rowptr[n + 1];
      float m = -1e30f;
      for (int i = rs; i < re; ++i)
        m = fmaxf(m, logits[(size_t)i * 4 + h]);
      float den = 0.f;
      float a0 = 0.f, a1 = 0.f, a2 = 0.f, a3 = 0.f;
      for (int i = rs; i < re; ++i) {
        float wgt = __expf(logits[(size_t)i * 4 + h] - m);
        den += wgt;
        ushort4 v = *(const ushort4*)(Vs + (size_t)i * 128 + d0);
        a0 = fmaf(wgt, b2f(v.x), a0);
        a1 = fmaf(wgt, b2f(v.y), a1);
        a2 = fmaf(wgt, b2f(v.z), a2);
        a3 = fmaf(wgt, b2f(v.w), a3);
      }
      float inv = (den > 0.f) ? (omb / den) : 0.f;
      ushort4 sv = *(const ushort4*)(S + (size_t)n * 128 + d0);
      float p0 = fmaf(beta, b2f(sv.x), a0 * inv);
      float p1 = fmaf(beta, b2f(sv.y), a1 * inv);
      float p2 = fmaf(beta, b2f(sv.z), a2 * inv);
      float p3 = fmaf(beta, b2f(sv.w), a3 * inv);
      if (PREBF16) {
        ushort4 o;
        o.x = f2bf(p0); o.y = f2bf(p1); o.z = f2bf(p2); o.w = f2bf(p3);
        *(ushort4*)(preb + (size_t)n * 128 + d0) = o;
      } else {
        *(float4*)(pre + (size_t)n * 128 + d0) = make_float4(p0, p1, p2, p3);
      }
      s4[0] += p0; s4[1] += p1; s4[2] += p2; s4[3] += p3;
      q4[0] += p0 * p0; q4[1] += p1 * p1; q4[2] += p2 * p2; q4[3] += p3 * p3;
    }
  }
  *(float4*)(&red[g * 128 + d0]) = make_float4(s4[0], s4[1], s4[2], s4[3]);
  __syncthreads();
  if (t < 128) {
    float tot = 0.f;
    #pragma unroll
    for (int gg = 0; gg < 8; ++gg) tot += red[gg * 128 + t];
    atomicAdd(&colsum[t], tot);
  }
  __syncthreads();
  *(float4*)(&red[g * 128 + d0]) = make_float4(q4[0], q4[1], q4[2], q4[3]);
  __syncthreads();
  if (t < 128) {
    float tot = 0.f;
    #pragma unroll
    for (int gg = 0; gg < 8; ++gg) tot += red[gg * 128 + t];
    atomicAdd(&colsumsq[t], tot);
  }
}

// ---------------- BatchNorm + ReLU for the LAST layer (f32 in d_out) ----------------
__global__ __launch_bounds__(256)
void bn_apply(const float* __restrict__ pre, const float* __restrict__ colsum,
              const float* __restrict__ colsumsq, const float* __restrict__ gamma,
              const float* __restrict__ bvec, float* __restrict__ outf)
{
  const int idx = blockIdx.x * 256 + threadIdx.x;
  const int n = idx >> 5;
  const int d0 = (idx & 31) * 4;
  const float invN = 1.f / 150000.f;
  float4 p = *(const float4*)(pre + (size_t)n * 128 + d0);
  float4 cs = *(const float4*)(colsum + d0);
  float4 cq = *(const float4*)(colsumsq + d0);
  float4 gm = *(const float4*)(gamma + d0);
  float4 bv = *(const float4*)(bvec + d0);
  float mu, var, y;
  mu = cs.x * invN; var = cq.x * invN - mu * mu;
  y = (p.x - mu) * rsqrtf(var + 1e-5f) * gm.x + bv.x; p.x = fmaxf(y, 0.f);
  mu = cs.y * invN; var = cq.y * invN - mu * mu;
  y = (p.y - mu) * rsqrtf(var + 1e-5f) * gm.y + bv.y; p.y = fmaxf(y, 0.f);
  mu = cs.z * invN; var = cq.z * invN - mu * mu;
  y = (p.z - mu) * rsqrtf(var + 1e-5f) * gm.z + bv.z; p.z = fmaxf(y, 0.f);
  mu = cs.w * invN; var = cq.w * invN - mu * mu;
  y = (p.w - mu) * rsqrtf(var + 1e-5f) * gm.w + bv.w; p.w = fmaxf(y, 0.f);
  *(float4*)(outf + (size_t)n * 128 + d0) = p;
}

extern "C" void kernel_launch(void* const* d_in, const int* in_sizes, int n_in,
                              void* d_out, int out_size, void* d_ws, size_t ws_size,
                              hipStream_t stream)
{
  const float* x0    = (const float*)d_in[0];
  const float* Wq    = (const float*)d_in[1];
  const float* Wk    = (const float*)d_in[2];
  const float* Wv    = (const float*)d_in[3];
  const float* Wsk   = (const float*)d_in[4];
  const float* Wa    = (const float*)d_in[5];
  const float* tw    = (const float*)d_in[6];
  const float* tb    = (const float*)d_in[7];
  const float* dw    = (const float*)d_in[8];
  const float* db    = (const float*)d_in[9];
  const float* ttab  = (const float*)d_in[10];
  const float* gam   = (const float*)d_in[11];
  const float* bet   = (const float*)d_in[12];
  const float* betaP = (const float*)d_in[13];
  const float* attr  = (const float*)d_in[14];
  const float* dt    = (const float*)d_in[15];
  const float* dsv   = (const float*)d_in[16];
  const int*   eidx  = (const int*)d_in[17];
  const int*   etyp  = (const int*)d_in[18];

  // workspace ~222 MB
  char* p = (char*)d_ws;
  u16* xbf  = (u16*)p;       p += 38400000;          // [N,128] bf16: pre of previous layer
  u16* Q    = (u16*)p;       p += 38400000;          // [N,128] bf16
  u16* S    = (u16*)p;       p += 38400000;          // [N,128] bf16
  u16* kvV  = (u16*)p;       p += 76800000;          // [E,128] bf16: kv_in, then V (in place)
  float* logits = (float*)p; p += 4800000;           // [E,4] f32 dst-sorted
  int* rowptr = (int*)p;     p += 4 * L_CNT * 4;
  int* tmp    = (int*)p;     p += 4 * L_CNT * 4;
  int* bsum   = (int*)p;     p += 4 * 128 * 4;
  float* colsum   = (float*)p; p += 512;
  float* colsumsq = (float*)p; p += 512;
  float* scsh     = (float*)p; p += 1024;            // {scale[128], shift[128]}
  u16* Wt = (u16*)p;         p += 16 * 16384 * 2;    // 16 transposed bf16 weights
  u32* metaA = (u32*)p;      p += (size_t)E_EDGES * 32;  // 32B/edge ping
  u32* metaB = (u32*)p;      p += (size_t)E_EDGES * 32;  // pong

  float* pre = (float*)d_out;   // [N,128] f32 scratch for LAST layer

  // weight transpose + CSR build (once) + layer-0 scatter
  k_wt<<<16, 256, 0, stream>>>(Wq, Wk, Wv, Wsk, Wt);
  hipMemsetAsync(tmp, 0, 4 * L_CNT * 4, stream);
  k_hist<<<dim3(1172, 4), 256, 0, stream>>>(eidx, tmp);
  k_scan1<<<dim3(74, 4), 256, 0, stream>>>(tmp, rowptr, bsum);
  k_scan2<<<4, 128, 0, stream>>>(bsum);
  k_scan3<<<dim3(592, 4), 256, 0, stream>>>(rowptr, tmp, bsum);
  k_scatter<<<SCATB, 256, 0, stream>>>(
      eidx, eidx + 300000, etyp, dt, dsv, attr, tmp, metaA);

  for (int l = 0; l < 4; ++l) {
    const int* rpl = rowptr + (size_t)l * L_CNT;
    const u16* WtQl = Wt + (size_t)l * 16384;
    const u16* WtKl = Wt + (size_t)(4 + l) * 16384;
    const u16* WtVl = Wt + (size_t)(8 + l) * 16384;
    const u16* WtSl = Wt + (size_t)(12 + l) * 16384;
    const float* Wal = Wa + (size_t)l * 1024;
    u32* metaCur = (l & 1) ? metaB : metaA;
    u32* metaNxt = (l & 1) ? metaA : metaB;
    const int ln = l + 1;
    const int* srcN = eidx + (size_t)ln * 600000;
    const int* dstN = srcN + 300000;

    hipMemsetAsync(colsum, 0, 1024, stream);

    if (l == 0) {
      prep<1, 0><<<NTILES + KVBLKS, 128, 0, stream>>>(
          (const void*)x0, WtQl, WtSl, scsh, Q, S,
          Wal, tw, tb, dw, db, ttab, metaCur, kvV);
    } else {
      prep<0, 1><<<NTILES + KVBLKS, 128, 0, stream>>>(
          (const void*)xbf, WtQl, WtSl, scsh, Q, S,
          Wal, tw, tb, dw, db, ttab, metaCur, kvV);
    }

    edge_kv<<<ETILES, 128, 0, stream>>>(WtKl, WtVl, metaCur, Q, kvV, logits);

    if (l < 3) {
      // node_agg + next-layer scatter packed into one launch
      node_agg<1><<<AGGB + SCATB, 256, 0, stream>>>(
          kvV, logits, rpl, S, betaP + l, nullptr, xbf, colsum, colsumsq,
          srcN, dstN, etyp + (size_t)ln * 300000, dt + (size_t)ln * 300000,
          dsv + (size_t)ln * 300000, attr + (size_t)ln * 2400000,
          tmp + (size_t)ln * L_CNT, metaNxt);
      bn_stats<<<1, 128, 0, stream>>>(colsum, colsumsq, gam + (size_t)l * 128,
                                      bet + (size_t)l * 128, scsh);
    } else {
      node_agg<0><<<AGGB, 256, 0, stream>>>(
          kvV, logits, rpl, S, betaP + l, pre, nullptr, colsum, colsumsq,
          nullptr, nullptr, nullptr, nullptr, nullptr, nullptr,
          nullptr, nullptr);
      bn_apply<<<18750, 256, 0, stream>>>(pre, colsum, colsumsq,
                                          gam + (size_t)l * 128,
                                          bet + (size_t)l * 128, (float*)d_out);
    }
  }
}

// Round 23
// 1414.734 us; speedup vs baseline: 1.0162x; 1.0006x over previous
//
#include <hip/hip_runtime.h>

typedef unsigned int u32;
typedef unsigned short u16;
typedef short bf16x8 __attribute__((ext_vector_type(8)));
typedef float f32x4 __attribute__((ext_vector_type(4)));

#define N_NODES 150000
#define E_EDGES 300000
#define L_CNT   151552   // 74*2048 padded per-layer node stride
#define ETILES  9375     // E/32
#define NTILES  4688     // ceil(N/32)
#define KVBLKS  37500    // E*16/128 chunks at 128 threads
#define AGGB    1172     // node_agg blocks
#define SCATB   1172     // scatter blocks (E/256)

__device__ __forceinline__ float blo(u32 u){ return __uint_as_float(u << 16); }
__device__ __forceinline__ float bhi(u32 u){ return __uint_as_float(u & 0xffff0000u); }
__device__ __forceinline__ float b2f(u16 h){ return __uint_as_float(((u32)h) << 16); }
__device__ __forceinline__ u16 f2bf(float f){
  u32 u = __float_as_uint(f);
  return (u16)((u + 0x7fffu + ((u >> 16) & 1u)) >> 16);   // RNE
}
__device__ __forceinline__ u32 pack2(float a, float b){
  return (u32)f2bf(a) | ((u32)f2bf(b) << 16);
}

__device__ __forceinline__ f32x4 mfma16(bf16x8 a, bf16x8 b, f32x4 c){
  return __builtin_amdgcn_mfma_f32_16x16x32_bf16(a, b, c, 0, 0, 0);
}

// operand tile [r=0..31][k=0..127] u16, XOR-swizzled
__device__ __forceinline__ int opsw(int r, int k){ return (r * 128 + k) ^ ((r & 7) << 3); }
// C tile [r][n] swizzle
__device__ __forceinline__ int csw(int r, int n){ return (r * 128 + n) ^ (((r >> 2) & 3) << 3); }

// ---------------- weight pre-transpose: Wt[n][k] bf16 <- W[k][n] f32 ----------------
__global__ __launch_bounds__(256)
void k_wt(const float* __restrict__ Wq, const float* __restrict__ Wk,
          const float* __restrict__ Wv, const float* __restrict__ Ws,
          u16* __restrict__ Wt)
{
  const int m = blockIdx.x;   // 0..15: [Wq0-3, Wk0-3, Wv0-3, Wsk0-3]
  const float* src = (m < 4 ? Wq : m < 8 ? Wk : m < 12 ? Wv : Ws)
                     + (size_t)(m & 3) * 16384;
  u16* dst = Wt + (size_t)m * 16384;
  const int t = threadIdx.x;
  for (int i = 0; i < 16; ++i) {
    int idx = i * 256 + t;
    int n = idx >> 5;
    int k4 = (idx & 31) << 2;
    ushort4 o;
    o.x = f2bf(src[(k4 + 0) * 128 + n]);
    o.y = f2bf(src[(k4 + 1) * 128 + n]);
    o.z = f2bf(src[(k4 + 2) * 128 + n]);
    o.w = f2bf(src[(k4 + 3) * 128 + n]);
    *(ushort4*)(dst + n * 128 + k4) = o;
  }
}

// ---------------- CSR build (counting sort of edges by dst) ----------------

__global__ __launch_bounds__(256)
void k_hist(const int* __restrict__ eidx, int* __restrict__ counts)
{
  const int l = blockIdx.y;
  const int e = blockIdx.x * 256 + threadIdx.x;
  if (e < E_EDGES) {
    int dst = eidx[(size_t)l * 2 * E_EDGES + E_EDGES + e];
    atomicAdd(&counts[(size_t)l * L_CNT + dst], 1);
  }
}

__global__ __launch_bounds__(256)
void k_scan1(const int* __restrict__ counts, int* __restrict__ rowptr,
             int* __restrict__ bsum)
{
  __shared__ int sh[256];
  const int b = blockIdx.x, l = blockIdx.y;
  const int t = threadIdx.x;
  const int* c = counts + (size_t)l * L_CNT + b * 2048;
  int* rp = rowptr + (size_t)l * L_CNT + b * 2048;
  int v[8]; int s = 0;
  #pragma unroll
  for (int j = 0; j < 8; ++j) { v[j] = c[t * 8 + j]; s += v[j]; }
  sh[t] = s; __syncthreads();
  for (int off = 1; off < 256; off <<= 1) {
    int x = (t >= off) ? sh[t - off] : 0;
    __syncthreads();
    sh[t] += x;
    __syncthreads();
  }
  int excl = (t == 0) ? 0 : sh[t - 1];
  if (t == 255) bsum[l * 128 + b] = sh[255];
  int run = excl;
  #pragma unroll
  for (int j = 0; j < 8; ++j) { rp[t * 8 + j] = run; run += v[j]; }
}

__global__ __launch_bounds__(128)
void k_scan2(int* __restrict__ bsum)
{
  __shared__ int sh[128];
  const int l = blockIdx.x, t = threadIdx.x;
  int v = (t < 74) ? bsum[l * 128 + t] : 0;
  sh[t] = v; __syncthreads();
  for (int off = 1; off < 128; off <<= 1) {
    int x = (t >= off) ? sh[t - off] : 0;
    __syncthreads();
    sh[t] += x;
    __syncthreads();
  }
  int excl = (t == 0) ? 0 : sh[t - 1];
  if (t < 74) bsum[l * 128 + t] = excl;
}

__global__ __launch_bounds__(256)
void k_scan3(int* __restrict__ rowptr, int* __restrict__ tmp,
             const int* __restrict__ bsum)
{
  const int l = blockIdx.y;
  const int q = blockIdx.x * 256 + threadIdx.x;
  int v = rowptr[(size_t)l * L_CNT + q] + bsum[l * 128 + (q >> 11)];
  rowptr[(size_t)l * L_CNT + q] = v;
  tmp[(size_t)l * L_CNT + q] = v;
}

// scatter device body: edge e -> dst-sorted 32B meta record
// r0 = {src, dst | et<<20, dt/24, ds}; r1 = attr as bf16x8.
__device__ __forceinline__ void scatter_one(
    int e, const int* __restrict__ srcP, const int* __restrict__ dstP,
    const int* __restrict__ etP, const float* __restrict__ dtP,
    const float* __restrict__ dsP, const float* __restrict__ attrP,
    int* __restrict__ tmpL, u32* __restrict__ meta)
{
  int dst = dstP[e];
  int pos = atomicAdd(&tmpL[dst], 1);
  int src = srcP[e];
  int et  = etP[e];
  float dtn = dtP[e] * (1.0f / 24.0f);
  float dsv = dsP[e];
  float4 aA = *(const float4*)(attrP + (size_t)e * 8);
  float4 aB = *(const float4*)(attrP + (size_t)e * 8 + 4);
  uint4 r0, r1;
  r0.x = (u32)src;
  r0.y = (u32)dst | ((u32)et << 20);
  r0.z = __float_as_uint(dtn);
  r0.w = __float_as_uint(dsv);
  r1.x = pack2(aA.x, aA.y); r1.y = pack2(aA.z, aA.w);
  r1.z = pack2(aB.x, aB.y); r1.w = pack2(aB.z, aB.w);
  u32* mp = meta + (size_t)pos * 8;
  *(uint4*)mp = r0;
  *(uint4*)(mp + 4) = r1;
}

__global__ __launch_bounds__(256)
void k_scatter(const int* __restrict__ srcP, const int* __restrict__ dstP,
               const int* __restrict__ etP, const float* __restrict__ dtP,
               const float* __restrict__ dsP, const float* __restrict__ attrP,
               int* __restrict__ tmpL, u32* __restrict__ meta)
{
  const int e = blockIdx.x * 256 + threadIdx.x;
  if (e < E_EDGES)
    scatter_one(e, srcP, dstP, etP, dtP, dsP, attrP, tmpL, meta);
}

// ---------------- BN stats fold: scsh = {scale[128], shift[128]} ----------------
__global__ __launch_bounds__(128)
void bn_stats(const float* __restrict__ colsum, const float* __restrict__ colsumsq,
              const float* __restrict__ gamma, const float* __restrict__ bvec,
              float* __restrict__ scsh)
{
  const int d = threadIdx.x;
  const float invN = 1.f / 150000.f;
  float mu = colsum[d] * invN;
  float var = colsumsq[d] * invN - mu * mu;
  float sc = gamma[d] * rsqrtf(var + 1e-5f);
  scsh[d] = sc;
  scsh[128 + d] = bvec[d] - mu * sc;
}

// ---------------- combined prep: gemm_qs blocks + kv_in blocks in ONE launch ----------
// blockIdx.x < NTILES : node GEMM tile (wave0 -> Q, wave1 -> S), proven body.
// blockIdx.x >= NTILES: kv_in feature chunks (128 threads), proven body.

template<int XF32, int BN>
__global__ __launch_bounds__(128, 2)
void prep(const void* __restrict__ xg, const u16* __restrict__ WtQ,
          const u16* __restrict__ WtS, const float* __restrict__ scsh,
          u16* __restrict__ Qo, u16* __restrict__ So,
          const float* __restrict__ Wa, const float* __restrict__ tw,
          const float* __restrict__ tb, const float* __restrict__ dw,
          const float* __restrict__ db, const float* __restrict__ ttab,
          const u32* __restrict__ meta, u16* __restrict__ kvV)
{
  __shared__ __align__(16) u16 As[4160];
  __shared__ __align__(16) u16 Bs[4160];
  const int t = threadIdx.x;

  if (blockIdx.x < NTILES) {
    // ---------------- node GEMM path ----------------
    const int w = t >> 6, lane = t & 63;
    const int lr = lane & 15, hi = lane >> 4;
    const int row0 = blockIdx.x * 32;
    const int nr = min(32, N_NODES - row0);
    const u16* Wt = w ? WtS : WtQ;
    u16* C = w ? So : Qo;

    bf16x8 wt[8][4];
    #pragma unroll
    for (int nb = 0; nb < 8; ++nb)
      #pragma unroll
      for (int ks = 0; ks < 4; ++ks)
        wt[nb][ks] = *(const bf16x8*)(Wt + (nb * 16 + lr) * 128 + ks * 32 + hi * 8);

    #pragma unroll
    for (int i = 0; i < 4; ++i) {
      int idx = i * 128 + t;
      int r = idx >> 4, c8 = (idx & 15) << 3;
      if (r < nr) {
        if (XF32) {
          float4 vA = *(const float4*)((const float*)xg + (size_t)(row0 + r) * 128 + c8);
          float4 vB = *(const float4*)((const float*)xg + (size_t)(row0 + r) * 128 + c8 + 4);
          uint4 o;
          o.x = pack2(vA.x, vA.y); o.y = pack2(vA.z, vA.w);
          o.z = pack2(vB.x, vB.y); o.w = pack2(vB.z, vB.w);
          *(uint4*)(As + opsw(r, c8)) = o;
        } else {
          uint4 v = *(const uint4*)((const u16*)xg + (size_t)(row0 + r) * 128 + c8);
          if (BN) {
            float4 scA = *(const float4*)(scsh + c8);
            float4 scB = *(const float4*)(scsh + c8 + 4);
            float4 shA = *(const float4*)(scsh + 128 + c8);
            float4 shB = *(const float4*)(scsh + 128 + c8 + 4);
            float e0v = fmaxf(fmaf(blo(v.x), scA.x, shA.x), 0.f);
            float e1v = fmaxf(fmaf(bhi(v.x), scA.y, shA.y), 0.f);
            float e2v = fmaxf(fmaf(blo(v.y), scA.z, shA.z), 0.f);
            float e3v = fmaxf(fmaf(bhi(v.y), scA.w, shA.w), 0.f);
            float e4v = fmaxf(fmaf(blo(v.z), scB.x, shB.x), 0.f);
            float e5v = fmaxf(fmaf(bhi(v.z), scB.y, shB.y), 0.f);
            float e6v = fmaxf(fmaf(blo(v.w), scB.z, shB.z), 0.f);
            float e7v = fmaxf(fmaf(bhi(v.w), scB.w, shB.w), 0.f);
            v.x = pack2(e0v, e1v); v.y = pack2(e2v, e3v);
            v.z = pack2(e4v, e5v); v.w = pack2(e6v, e7v);
          }
          *(uint4*)(As + opsw(r, c8)) = v;
        }
      } else {
        *(uint4*)(As + opsw(r, c8)) = make_uint4(0, 0, 0, 0);
      }
    }
    __syncthreads();

    f32x4 acc[2][8];
    #pragma unroll
    for (int a = 0; a < 2; ++a)
      #pragma unroll
      for (int b = 0; b < 8; ++b) {
        acc[a][b][0] = 0.f; acc[a][b][1] = 0.f;
        acc[a][b][2] = 0.f; acc[a][b][3] = 0.f;
      }
    #pragma unroll
    for (int ks = 0; ks < 4; ++ks) {
      const int kb = ks * 32 + hi * 8;
      bf16x8 a0 = *(const bf16x8*)(As + opsw(lr, kb));
      bf16x8 a1 = *(const bf16x8*)(As + opsw(16 + lr, kb));
      #pragma unroll
      for (int nb = 0; nb < 8; ++nb) {
        acc[0][nb] = mfma16(a0, wt[nb][ks], acc[0][nb]);
        acc[1][nb] = mfma16(a1, wt[nb][ks], acc[1][nb]);
      }
    }
    __syncthreads();   // all As reads complete before wave0 overwrites it

    u16* Cs = w ? Bs : As;
    const int g4 = hi << 2;
    #pragma unroll
    for (int mt = 0; mt < 2; ++mt)
      #pragma unroll
      for (int nt = 0; nt < 8; ++nt)
        #pragma unroll
        for (int j = 0; j < 4; ++j)
          Cs[csw(mt * 16 + g4 + j, nt * 16 + lr)] = f2bf(acc[mt][nt][j]);
    #pragma unroll
    for (int i = 0; i < 8; ++i) {
      int idx = i * 64 + lane;
      int r = idx >> 4, n8 = (idx & 15) << 3;
      if (r < nr) {
        uint4 v = *(const uint4*)(Cs + csw(r, n8));
        *(uint4*)(C + (size_t)(row0 + r) * 128 + n8) = v;
      }
    }
  } else {
    // ---------------- kv_in path (one 8-dim chunk per thread) ----------------
    const int idx = (blockIdx.x - NTILES) * 128 + t;   // E*16 chunks
    const int e = idx >> 4;
    const int c8 = (idx & 15) << 3;
    const u32* mp = meta + (size_t)e * 8;
    uint4 m0 = *(const uint4*)mp;
    uint4 m1 = *(const uint4*)(mp + 4);
    const int src = (int)m0.x;
    const int et = (int)(m0.y >> 20);
    const float dtn = __uint_as_float(m0.z);
    const float dss = __uint_as_float(m0.w);
    float aa[8] = { blo(m1.x), bhi(m1.x), blo(m1.y), bhi(m1.y),
                    blo(m1.z), bhi(m1.z), blo(m1.w), bhi(m1.w) };
    const float4 twA = *(const float4*)(tw + c8);
    const float4 twB = *(const float4*)(tw + c8 + 4);
    const float4 tbA = *(const float4*)(tb + c8);
    const float4 tbB = *(const float4*)(tb + c8 + 4);
    const float4 dwA = *(const float4*)(dw + c8);
    const float4 dwB = *(const float4*)(dw + c8 + 4);
    const float4 dbA = *(const float4*)(db + c8);
    const float4 dbB = *(const float4*)(db + c8 + 4);
    const float4 ttA = *(const float4*)(ttab + et * 128 + c8);
    const float4 ttB = *(const float4*)(ttab + et * 128 + c8 + 4);
    float f[8];
    f[0] = __cosf(fmaf(dtn, twA.x, tbA.x)) + __cosf(fmaf(dss, dwA.x, dbA.x)) + ttA.x;
    f[1] = __cosf(fmaf(dtn, twA.y, tbA.y)) + __cosf(fmaf(dss, dwA.y, dbA.y)) + ttA.y;
    f[2] = __cosf(fmaf(dtn, twA.z, tbA.z)) + __cosf(fmaf(dss, dwA.z, dbA.z)) + ttA.z;
    f[3] = __cosf(fmaf(dtn, twA.w, tbA.w)) + __cosf(fmaf(dss, dwA.w, dbA.w)) + ttA.w;
    f[4] = __cosf(fmaf(dtn, twB.x, tbB.x)) + __cosf(fmaf(dss, dwB.x, dbB.x)) + ttB.x;
    f[5] = __cosf(fmaf(dtn, twB.y, tbB.y)) + __cosf(fmaf(dss, dwB.y, dbB.y)) + ttB.y;
    f[6] = __cosf(fmaf(dtn, twB.z, tbB.z)) + __cosf(fmaf(dss, dwB.z, dbB.z)) + ttB.z;
    f[7] = __cosf(fmaf(dtn, twB.w, tbB.w)) + __cosf(fmaf(dss, dwB.w, dbB.w)) + ttB.w;
    #pragma unroll
    for (int a = 0; a < 8; ++a) {
      float4 wA = *(const float4*)(Wa + a * 128 + c8);
      float4 wB = *(const float4*)(Wa + a * 128 + c8 + 4);
      f[0] = fmaf(aa[a], wA.x, f[0]);
      f[1] = fmaf(aa[a], wA.y, f[1]);
      f[2] = fmaf(aa[a], wA.z, f[2]);
      f[3] = fmaf(aa[a], wA.w, f[3]);
      f[4] = fmaf(aa[a], wB.x, f[4]);
      f[5] = fmaf(aa[a], wB.y, f[5]);
      f[6] = fmaf(aa[a], wB.z, f[6]);
      f[7] = fmaf(aa[a], wB.w, f[7]);
    }
    float xv[8];
    if (XF32) {
      float4 xA = *(const float4*)((const float*)xg + (size_t)src * 128 + c8);
      float4 xB = *(const float4*)((const float*)xg + (size_t)src * 128 + c8 + 4);
      xv[0] = xA.x; xv[1] = xA.y; xv[2] = xA.z; xv[3] = xA.w;
      xv[4] = xB.x; xv[5] = xB.y; xv[6] = xB.z; xv[7] = xB.w;
    } else {
      uint4 xr = *(const uint4*)((const u16*)xg + (size_t)src * 128 + c8);
      xv[0] = blo(xr.x); xv[1] = bhi(xr.x); xv[2] = blo(xr.y); xv[3] = bhi(xr.y);
      xv[4] = blo(xr.z); xv[5] = bhi(xr.z); xv[6] = blo(xr.w); xv[7] = bhi(xr.w);
    }
    if (BN) {
      float4 scA = *(const float4*)(scsh + c8);
      float4 scB = *(const float4*)(scsh + c8 + 4);
      float4 shA = *(const float4*)(scsh + 128 + c8);
      float4 shB = *(const float4*)(scsh + 128 + c8 + 4);
      xv[0] = fmaxf(fmaf(xv[0], scA.x, shA.x), 0.f);
      xv[1] = fmaxf(fmaf(xv[1], scA.y, shA.y), 0.f);
      xv[2] = fmaxf(fmaf(xv[2], scA.z, shA.z), 0.f);
      xv[3] = fmaxf(fmaf(xv[3], scA.w, shA.w), 0.f);
      xv[4] = fmaxf(fmaf(xv[4], scB.x, shB.x), 0.f);
      xv[5] = fmaxf(fmaf(xv[5], scB.y, shB.y), 0.f);
      xv[6] = fmaxf(fmaf(xv[6], scB.z, shB.z), 0.f);
      xv[7] = fmaxf(fmaf(xv[7], scB.w, shB.w), 0.f);
    }
    uint4 o;
    o.x = pack2(xv[0] + f[0], xv[1] + f[1]);
    o.y = pack2(xv[2] + f[2], xv[3] + f[3]);
    o.z = pack2(xv[4] + f[4], xv[5] + f[5]);
    o.w = pack2(xv[6] + f[6], xv[7] + f[7]);
    *(uint4*)(kvV + (size_t)e * 128 + c8) = o;
  }
}

// ---------------- edge fused: wave0 = kv-stage + K + logits, wave1 = Q-stage + V ------
// Single tile per block (proven: VGPR 104, no spill, 119 us).

__global__ __launch_bounds__(128, 2)
void edge_kv(const u16* __restrict__ WtK, const u16* __restrict__ WtV,
             const u32* __restrict__ meta, const u16* __restrict__ Qb,
             u16* __restrict__ kvV, float* __restrict__ logits)
{
  __shared__ __align__(16) u16 KVs[4160];  // kv tile
  __shared__ __align__(16) u16 Qs[4160];   // Q[dst] tile; wave1's V C-tile later
  __shared__ int dstSh[32];
  const int t = threadIdx.x;
  const int w = t >> 6, lane = t & 63;
  const int lr = lane & 15, hi = lane >> 4;
  const int e0 = blockIdx.x * 32;
  const u16* Wt = w ? WtV : WtK;

  bf16x8 wt[8][4];
  #pragma unroll
  for (int nb = 0; nb < 8; ++nb)
    #pragma unroll
    for (int ks = 0; ks < 4; ++ks)
      wt[nb][ks] = *(const bf16x8*)(Wt + (nb * 16 + lr) * 128 + ks * 32 + hi * 8);

  if (w == 0) {
    #pragma unroll
    for (int i = 0; i < 8; ++i) {
      int idx = i * 64 + lane;
      int r = idx >> 4, c8 = (idx & 15) << 3;
      uint4 v = *(const uint4*)(kvV + (size_t)(e0 + r) * 128 + c8);
      *(uint4*)(KVs + opsw(r, c8)) = v;
    }
  } else {
    if (lane < 32)
      dstSh[lane] = (int)(meta[(size_t)(e0 + lane) * 8 + 1] & 0xFFFFFu);
    #pragma unroll
    for (int i = 0; i < 8; ++i) {
      int idx = i * 64 + lane;
      int r = idx >> 4, c8 = (idx & 15) << 3;
      int qrow = dstSh[r];
      uint4 qv = *(const uint4*)(Qb + (size_t)qrow * 128 + c8);
      *(uint4*)(Qs + opsw(r, c8)) = qv;
    }
  }
  __syncthreads();

  if (w == 0) {
    #pragma unroll
    for (int eb = 0; eb < 2; ++eb) {
      f32x4 kacc[8];
      #pragma unroll
      for (int b = 0; b < 8; ++b) {
        kacc[b][0] = 0.f; kacc[b][1] = 0.f; kacc[b][2] = 0.f; kacc[b][3] = 0.f;
      }
      #pragma unroll
      for (int ks = 0; ks < 4; ++ks) {
        bf16x8 ef = *(const bf16x8*)(KVs + opsw(eb * 16 + lr, ks * 32 + hi * 8));
        #pragma unroll
        for (int nb = 0; nb < 8; ++nb)
          kacc[nb] = mfma16(wt[nb][ks], ef, kacc[nb]);
      }
      const int el = eb * 16 + lr;
      float hs[4] = {0.f, 0.f, 0.f, 0.f};
      #pragma unroll
      for (int nb = 0; nb < 8; ++nb) {
        ushort4 q = *(const ushort4*)(Qs + opsw(el, nb * 16 + hi * 4));
        hs[nb >> 1] += b2f(q.x) * kacc[nb][0] + b2f(q.y) * kacc[nb][1]
                     + b2f(q.z) * kacc[nb][2] + b2f(q.w) * kacc[nb][3];
      }
      #pragma unroll
      for (int h = 0; h < 4; ++h) {
        hs[h] += __shfl_xor(hs[h], 16, 64);
        hs[h] += __shfl_xor(hs[h], 32, 64);
        hs[h] *= 0.17677669529663687f;                 // 32^-0.5
        hs[h] = (hs[h] >= 0.f) ? hs[h] : 0.2f * hs[h]; // leaky relu
      }
      if (lane < 16)
        *(float4*)(logits + (size_t)(e0 + el) * 4) = make_float4(hs[0], hs[1], hs[2], hs[3]);
    }
    __syncthreads();   // pairs with wave1's barrier: Qs now free for its C tile
  } else {
    f32x4 vacc[2][8];
    #pragma unroll
    for (int a = 0; a < 2; ++a)
      #pragma unroll
      for (int b = 0; b < 8; ++b) {
        vacc[a][b][0] = 0.f; vacc[a][b][1] = 0.f;
        vacc[a][b][2] = 0.f; vacc[a][b][3] = 0.f;
      }
    #pragma unroll
    for (int ks = 0; ks < 4; ++ks) {
      const int kb = ks * 32 + hi * 8;
      bf16x8 a0 = *(const bf16x8*)(KVs + opsw(lr, kb));
      bf16x8 a1 = *(const bf16x8*)(KVs + opsw(16 + lr, kb));
      #pragma unroll
      for (int nb = 0; nb < 8; ++nb) {
        vacc[0][nb] = mfma16(a0, wt[nb][ks], vacc[0][nb]);
        vacc[1][nb] = mfma16(a1, wt[nb][ks], vacc[1][nb]);
      }
    }
    __syncthreads();   // wave0 done reading Qs -> reuse as C tile
    const int g4 = hi << 2;
    #pragma unroll
    for (int mt = 0; mt < 2; ++mt)
      #pragma unroll
      for (int nt = 0; nt < 8; ++nt)
        #pragma unroll
        for (int j = 0; j < 4; ++j)
          Qs[csw(mt * 16 + g4 + j, nt * 16 + lr)] = f2bf(vacc[mt][nt][j]);
    #pragma unroll
    for (int i = 0; i < 8; ++i) {
      int idx = i * 64 + lane;
      int r = idx >> 4, n8 = (idx & 15) << 3;
      uint4 v = *(const uint4*)(Qs + csw(r, n8));
      *(uint4*)(kvV + (size_t)(e0 + r) * 128 + n8) = v;
    }
  }
}

// ---------------- per-node softmax + aggregate + combine + stats ----------------
// blockIdx.x >= AGGB: next-layer scatter blocks (metaN != nullptr only for l<3).
template<int PREBF16>
__global__ __launch_bounds__(256)
void node_agg(const u16* __restrict__ Vs, const float* __restrict__ logits,
              const int* __restrict__ rowptr, const u16* __restrict__ S,
              const float* __restrict__ betaP, float* __restrict__ pre,
              u16* __restrict__ preb, float* __restrict__ colsum,
              float* __restrict__ colsumsq,
              const int* __restrict__ srcN, const int* __restrict__ dstN,
              const int* __restrict__ etN, const float* __restrict__ dtN,
              const float* __restrict__ dsN, const float* __restrict__ attrN,
              int* __restrict__ tmpN, u32* __restrict__ metaN)
{
  if (blockIdx.x >= AGGB) {
    int e = (int)(blockIdx.x - AGGB) * 256 + threadIdx.x;
    if (metaN != nullptr && e < E_EDGES)
      scatter_one(e, srcN, dstN, etN, dtN, dsN, attrN, tmpN, metaN);
    return;
  }

  __shared__ float red[1024];
  const int t = threadIdx.x;
  const int g = t >> 5;
  const int lane = t & 31;
  const int d0 = lane * 4;
  const int h = lane >> 3;
  const float beta = *betaP;
  const float omb = 1.f - beta;
  float s4[4] = {0.f, 0.f, 0.f, 0.f};
  float q4[4] = {0.f, 0.f, 0.f, 0.f};
  for (int rep = 0; rep < 16; ++rep) {
    int n = blockIdx.x * 128 + rep * 8 + g;
    if (n < N_NODES) {
      int rs = rowptr[n], re = rowptr[n + 1];
      float m = -1e30f;
      for (int i = rs; i < re; ++i)
        m = fmaxf(m, logits[(size_t)i * 4 + h]);
      float den = 0.f;
      float a0 = 0.f, a1 = 0.f, a2 = 0.f, a3 = 0.f;
      for (int i = rs; i < re; ++i) {
        float wgt = __expf(logits[(size_t)i * 4 + h] - m);
        den += wgt;
        ushort4 v = *(const ushort4*)(Vs + (size_t)i * 128 + d0);
        a0 = fmaf(wgt, b2f(v.x), a0);
        a1 = fmaf(wgt, b2f(v.y), a1);
        a2 = fmaf(wgt, b2f(v.z), a2);
        a3 = fmaf(wgt, b2f(v.w), a3);
      }
      float inv = (den > 0.f) ? (omb / den) : 0.f;
      ushort4 sv = *(const ushort4*)(S + (size_t)n * 128 + d0);
      float p0 = fmaf(beta, b2f(sv.x), a0 * inv);
      float p1 = fmaf(beta, b2f(sv.y), a1 * inv);
      float p2 = fmaf(beta, b2f(sv.z), a2 * inv);
      float p3 = fmaf(beta, b2f(sv.w), a3 * inv);
      if (PREBF16) {
        ushort4 o;
        o.x = f2bf(p0); o.y = f2bf(p1); o.z = f2bf(p2); o.w = f2bf(p3);
        *(ushort4*)(preb + (size_t)n * 128 + d0) = o;
      } else {
        *(float4*)(pre + (size_t)n * 128 + d0) = make_float4(p0, p1, p2, p3);
      }
      s4[0] += p0; s4[1] += p1; s4[2] += p2; s4[3] += p3;
      q4[0] += p0 * p0; q4[1] += p1 * p1; q4[2] += p2 * p2; q4[3] += p3 * p3;
    }
  }
  *(float4*)(&red[g * 128 + d0]) = make_float4(s4[0], s4[1], s4[2], s4[3]);
  __syncthreads();
  if (t < 128) {
    float tot = 0.f;
    #pragma unroll
    for (int gg = 0; gg < 8; ++gg) tot += red[gg * 128 + t];
    atomicAdd(&colsum[t], tot);
  }
  __syncthreads();
  *(float4*)(&red[g * 128 + d0]) = make_float4(q4[0], q4[1], q4[2], q4[3]);
  __syncthreads();
  if (t < 128) {
    float tot = 0.f;
    #pragma unroll
    for (int gg = 0; gg < 8; ++gg) tot += red[gg * 128 + t];
    atomicAdd(&colsumsq[t], tot);
  }
}

// ---------------- BatchNorm + ReLU for the LAST layer (f32 in d_out) ----------------
__global__ __launch_bounds__(256)
void bn_apply(const float* __restrict__ pre, const float* __restrict__ colsum,
              const float* __restrict__ colsumsq, const float* __restrict__ gamma,
              const float* __restrict__ bvec, float* __restrict__ outf)
{
  const int idx = blockIdx.x * 256 + threadIdx.x;
  const int n = idx >> 5;
  const int d0 = (idx & 31) * 4;
  const float invN = 1.f / 150000.f;
  float4 p = *(const float4*)(pre + (size_t)n * 128 + d0);
  float4 cs = *(const float4*)(colsum + d0);
  float4 cq = *(const float4*)(colsumsq + d0);
  float4 gm = *(const float4*)(gamma + d0);
  float4 bv = *(const float4*)(bvec + d0);
  float mu, var, y;
  mu = cs.x * invN; var = cq.x * invN - mu * mu;
  y = (p.x - mu) * rsqrtf(var + 1e-5f) * gm.x + bv.x; p.x = fmaxf(y, 0.f);
  mu = cs.y * invN; var = cq.y * invN - mu * mu;
  y = (p.y - mu) * rsqrtf(var + 1e-5f) * gm.y + bv.y; p.y = fmaxf(y, 0.f);
  mu = cs.z * invN; var = cq.z * invN - mu * mu;
  y = (p.z - mu) * rsqrtf(var + 1e-5f) * gm.z + bv.z; p.z = fmaxf(y, 0.f);
  mu = cs.w * invN; var = cq.w * invN - mu * mu;
  y = (p.w - mu) * rsqrtf(var + 1e-5f) * gm.w + bv.w; p.w = fmaxf(y, 0.f);
  *(float4*)(outf + (size_t)n * 128 + d0) = p;
}

extern "C" void kernel_launch(void* const* d_in, const int* in_sizes, int n_in,
                              void* d_out, int out_size, void* d_ws, size_t ws_size,
                              hipStream_t stream)
{
  const float* x0    = (const float*)d_in[0];
  const float* Wq    = (const float*)d_in[1];
  const float* Wk    = (const float*)d_in[2];
  const float* Wv    = (const float*)d_in[3];
  const float* Wsk   = (const float*)d_in[4];
  const float* Wa    = (const float*)d_in[5];
  const float* tw    = (const float*)d_in[6];
  const float* tb    = (const float*)d_in[7];
  const float* dw    = (const float*)d_in[8];
  const float* db    = (const float*)d_in[9];
  const float* ttab  = (const float*)d_in[10];
  const float* gam   = (const float*)d_in[11];
  const float* bet   = (const float*)d_in[12];
  const float* betaP = (const float*)d_in[13];
  const float* attr  = (const float*)d_in[14];
  const float* dt    = (const float*)d_in[15];
  const float* dsv   = (const float*)d_in[16];
  const int*   eidx  = (const int*)d_in[17];
  const int*   etyp  = (const int*)d_in[18];

  // workspace ~222 MB
  char* p = (char*)d_ws;
  u16* xbf  = (u16*)p;       p += 38400000;          // [N,128] bf16: pre of previous layer
  u16* Q    = (u16*)p;       p += 38400000;          // [N,128] bf16
  u16* S    = (u16*)p;       p += 38400000;          // [N,128] bf16
  u16* kvV  = (u16*)p;       p += 76800000;          // [E,128] bf16: kv_in, then V (in place)
  float* logits = (float*)p; p += 4800000;           // [E,4] f32 dst-sorted
  int* rowptr = (int*)p;     p += 4 * L_CNT * 4;
  int* tmp    = (int*)p;     p += 4 * L_CNT * 4;
  int* bsum   = (int*)p;     p += 4 * 128 * 4;
  float* colsum   = (float*)p; p += 512;
  float* colsumsq = (float*)p; p += 512;
  float* scsh     = (float*)p; p += 1024;            // {scale[128], shift[128]}
  u16* Wt = (u16*)p;         p += 16 * 16384 * 2;    // 16 transposed bf16 weights
  u32* metaA = (u32*)p;      p += (size_t)E_EDGES * 32;  // 32B/edge ping
  u32* metaB = (u32*)p;      p += (size_t)E_EDGES * 32;  // pong

  float* pre = (float*)d_out;   // [N,128] f32 scratch for LAST layer

  // weight transpose + CSR build (once) + layer-0 scatter
  k_wt<<<16, 256, 0, stream>>>(Wq, Wk, Wv, Wsk, Wt);
  hipMemsetAsync(tmp, 0, 4 * L_CNT * 4, stream);
  k_hist<<<dim3(1172, 4), 256, 0, stream>>>(eidx, tmp);
  k_scan1<<<dim3(74, 4), 256, 0, stream>>>(tmp, rowptr, bsum);
  k_scan2<<<4, 128, 0, stream>>>(bsum);
  k_scan3<<<dim3(592, 4), 256, 0, stream>>>(rowptr, tmp, bsum);
  k_scatter<<<SCATB, 256, 0, stream>>>(
      eidx, eidx + 300000, etyp, dt, dsv, attr, tmp, metaA);

  for (int l = 0; l < 4; ++l) {
    const int* rpl = rowptr + (size_t)l * L_CNT;
    const u16* WtQl = Wt + (size_t)l * 16384;
    const u16* WtKl = Wt + (size_t)(4 + l) * 16384;
    const u16* WtVl = Wt + (size_t)(8 + l) * 16384;
    const u16* WtSl = Wt + (size_t)(12 + l) * 16384;
    const float* Wal = Wa + (size_t)l * 1024;
    u32* metaCur = (l & 1) ? metaB : metaA;
    u32* metaNxt = (l & 1) ? metaA : metaB;
    const int ln = l + 1;
    const int* srcN = eidx + (size_t)ln * 600000;
    const int* dstN = srcN + 300000;

    hipMemsetAsync(colsum, 0, 1024, stream);

    if (l == 0) {
      prep<1, 0><<<NTILES + KVBLKS, 128, 0, stream>>>(
          (const void*)x0, WtQl, WtSl, scsh, Q, S,
          Wal, tw, tb, dw, db, ttab, metaCur, kvV);
    } else {
      prep<0, 1><<<NTILES + KVBLKS, 128, 0, stream>>>(
          (const void*)xbf, WtQl, WtSl, scsh, Q, S,
          Wal, tw, tb, dw, db, ttab, metaCur, kvV);
    }

    edge_kv<<<ETILES, 128, 0, stream>>>(WtKl, WtVl, metaCur, Q, kvV, logits);

    if (l < 3) {
      // node_agg + next-layer scatter packed into one launch
      node_agg<1><<<AGGB + SCATB, 256, 0, stream>>>(
          kvV, logits, rpl, S, betaP + l, nullptr, xbf, colsum, colsumsq,
          srcN, dstN, etyp + (size_t)ln * 300000, dt + (size_t)ln * 300000,
          dsv + (size_t)ln * 300000, attr + (size_t)ln * 2400000,
          tmp + (size_t)ln * L_CNT, metaNxt);
      bn_stats<<<1, 128, 0, stream>>>(colsum, colsumsq, gam + (size_t)l * 128,
                                      bet + (size_t)l * 128, scsh);
    } else {
      node_agg<0><<<AGGB, 256, 0, stream>>>(
          kvV, logits, rpl, S, betaP + l, pre, nullptr, colsum, colsumsq,
          nullptr, nullptr, nullptr, nullptr, nullptr, nullptr,
          nullptr, nullptr);
      bn_apply<<<18750, 256, 0, stream>>>(pre, colsum, colsumsq,
                                          gam + (size_t)l * 128,
                                          bet + (size_t)l * 128, (float*)d_out);
    }
  }
}